// Round 1
// baseline (2465.103 us; speedup 1.0000x reference)
//
#include <hip/hip_runtime.h>
#include <cstdint>
#include <cstddef>

#define S_LEN  2048
#define D_MODEL 1024
#define D_FF   2048
#define NLAYER 4
// H=8, DK=128, WINDOW=64 (half=32)

typedef float  f32x4  __attribute__((ext_vector_type(4)));
typedef __bf16 bf16x8 __attribute__((ext_vector_type(8)));

__device__ __forceinline__ void async_copy16(const void* g, void* s) {
    __builtin_amdgcn_global_load_lds((const __attribute__((address_space(1))) void*)g,
                                     (__attribute__((address_space(3))) void*)s, 16, 0, 0);
}

template<int NW>
__device__ __forceinline__ float blockRedSum(float v, float* red) {
    #pragma unroll
    for (int off = 32; off > 0; off >>= 1) v += __shfl_down(v, off);
    const int t = threadIdx.x;
    if ((t & 63) == 0) red[t >> 6] = v;
    __syncthreads();
    float r = red[0];
    #pragma unroll
    for (int i = 1; i < NW; i++) r += red[i];
    __syncthreads();
    return r;
}

template<int NW>
__device__ __forceinline__ float blockRedMax(float v, float* red) {
    #pragma unroll
    for (int off = 32; off > 0; off >>= 1) v = fmaxf(v, __shfl_down(v, off));
    const int t = threadIdx.x;
    if ((t & 63) == 0) red[t >> 6] = v;
    __syncthreads();
    float r = red[0];
    #pragma unroll
    for (int i = 1; i < NW; i++) r = fmaxf(r, red[i]);
    __syncthreads();
    return r;
}

// x = 2*enc + sinusoidal_pe; writes fp32 + bf16
__global__ __launch_bounds__(256)
void init_x_kernel(const float* __restrict__ enc, float* __restrict__ x, __bf16* __restrict__ xb) {
    const int s = blockIdx.x, t = threadIdx.x;
    #pragma unroll
    for (int i = 0; i < 4; i++) {
        const int d = t + i * 256;
        const float freq = expf(-(float)(d & ~1) * (9.210340371976184f / 1024.0f));
        const float ang = (float)s * freq;
        const float pe = (d & 1) ? cosf(ang) : sinf(ang);
        const float v = 2.0f * enc[(size_t)s * D_MODEL + d] + pe;
        x[(size_t)s * D_MODEL + d] = v;
        xb[(size_t)s * D_MODEL + d] = (__bf16)v;
    }
}

// is_global flags + compacted global column list
__global__ void mask_setup_kernel(const int* __restrict__ gidx, int* __restrict__ isg,
                                  int* __restrict__ gcols, int* __restrict__ ngc) {
    const int t = threadIdx.x;
    for (int s = t; s < S_LEN; s += 256) {
        int f = 0;
        for (int i = 0; i < 32; i++) {
            const int g = gidx[i] / 15;   // gidx >= 0
            if (g >= 0 && g < S_LEN && g == s) f = 1;
        }
        isg[s] = f;
    }
    __syncthreads();
    if (t == 0) {
        int n = 0;
        for (int s = 0; s < S_LEN; s++) if (isg[s]) gcols[n++] = s;
        *ngc = n;
    }
}

// W fp32 [K][N] -> Wt bf16 [N][K]
__global__ __launch_bounds__(256)
void transpose_bf16_kernel(const float* __restrict__ in, __bf16* __restrict__ out, int K, int N) {
    __shared__ float tile[32][33];
    const int tx = threadIdx.x, ty = threadIdx.y;
    const int n0 = blockIdx.x * 32, k0 = blockIdx.y * 32;
    #pragma unroll
    for (int i = ty; i < 32; i += 8)
        tile[i][tx] = in[(size_t)(k0 + i) * N + n0 + tx];
    __syncthreads();
    #pragma unroll
    for (int i = ty; i < 32; i += 8)
        out[(size_t)(n0 + i) * K + k0 + tx] = (__bf16)tile[tx][i];
}

// C[M][N] = A[M][K] * Bt[N][K]^T ; EPI 0: fp32 out, 1: relu->bf16 out
template<int EPI>
__global__ __launch_bounds__(256)
void gemm_bt(const __bf16* __restrict__ A, const __bf16* __restrict__ Bt,
             void* __restrict__ Cv, int M, int N, int K) {
    __shared__ __bf16 As[128 * 32];
    __shared__ __bf16 Bs[128 * 32];
    const int t = threadIdx.x;
    const int w = t >> 6, l = t & 63;
    const int l15 = l & 15, q4 = l >> 4;
    const int wr = w >> 1, wc = w & 1;
    const int m0 = blockIdx.y * 128, n0 = blockIdx.x * 128;

    const int row = t >> 2;          // 0..63
    const int kc  = (t & 3) * 8;     // element offset in K-tile
    const __bf16* ag0 = A  + (size_t)(m0 + row) * K + kc;
    const __bf16* ag1 = A  + (size_t)(m0 + row + 64) * K + kc;
    const __bf16* bg0 = Bt + (size_t)(n0 + row) * K + kc;
    const __bf16* bg1 = Bt + (size_t)(n0 + row + 64) * K + kc;
    __bf16* asw = As + w * 512;      // wave-uniform LDS base (bytes: w*1024)
    __bf16* bsw = Bs + w * 512;

    const int aoff = (wr * 64 + l15) * 32 + q4 * 8;
    const int boff = (wc * 64 + l15) * 32 + q4 * 8;

    f32x4 acc[4][4];
    #pragma unroll
    for (int i = 0; i < 4; i++)
        #pragma unroll
        for (int j = 0; j < 4; j++) acc[i][j] = (f32x4){0.f, 0.f, 0.f, 0.f};

    for (int k0 = 0; k0 < K; k0 += 32) {
        async_copy16(ag0 + k0, asw);
        async_copy16(ag1 + k0, asw + 2048);
        async_copy16(bg0 + k0, bsw);
        async_copy16(bg1 + k0, bsw + 2048);
        __syncthreads();
        bf16x8 af[4], bfr[4];
        #pragma unroll
        for (int i = 0; i < 4; i++) af[i]  = *(const bf16x8*)(As + aoff + i * 512);
        #pragma unroll
        for (int j = 0; j < 4; j++) bfr[j] = *(const bf16x8*)(Bs + boff + j * 512);
        #pragma unroll
        for (int i = 0; i < 4; i++)
            #pragma unroll
            for (int j = 0; j < 4; j++)
                acc[i][j] = __builtin_amdgcn_mfma_f32_16x16x32_bf16(af[i], bfr[j], acc[i][j], 0, 0, 0);
        __syncthreads();
    }

    const int r0 = m0 + wr * 64 + q4 * 4;
    const int c0 = n0 + wc * 64 + l15;
    if (EPI == 0) {
        float* C = (float*)Cv;
        #pragma unroll
        for (int i = 0; i < 4; i++)
            #pragma unroll
            for (int j = 0; j < 4; j++)
                #pragma unroll
                for (int r = 0; r < 4; r++)
                    C[(size_t)(r0 + i * 16 + r) * N + c0 + j * 16] = acc[i][j][r];
    } else {
        __bf16* C = (__bf16*)Cv;
        #pragma unroll
        for (int i = 0; i < 4; i++)
            #pragma unroll
            for (int j = 0; j < 4; j++)
                #pragma unroll
                for (int r = 0; r < 4; r++)
                    C[(size_t)(r0 + i * 16 + r) * N + c0 + j * 16] = (__bf16)fmaxf(acc[i][j][r], 0.0f);
    }
}

__global__ void zero_f_kernel(float* p, int n) {
    const int i = blockIdx.x * 256 + threadIdx.x;
    if (i < n) p[i] = 0.0f;
}

// column sums of V (qkv cols 2048..3071) -> vmean (holds SUM over all 2048 rows)
__global__ __launch_bounds__(256)
void vmean_kernel(const float* __restrict__ qkv, float* __restrict__ vmean) {
    const int d = blockIdx.x * 256 + threadIdx.x;      // 0..1023
    const int s0 = blockIdx.y * 128;
    float s = 0.f;
    for (int i = 0; i < 128; i++) s += qkv[(size_t)(s0 + i) * 3072 + 2048 + d];
    atomicAdd(&vmean[d], s);
}

// local-global masked attention. qkv [S][3072] fp32, ctx [S][1024] bf16.
__global__ __launch_bounds__(128)
void attn_kernel(const float* __restrict__ qkv, const int* __restrict__ Tp,
                 const int* __restrict__ isg, const int* __restrict__ gcols,
                 const int* __restrict__ ngcp, const float* __restrict__ vmean,
                 __bf16* __restrict__ ctx) {
    const int qrow = blockIdx.x, h = blockIdx.y, t = threadIdx.x;
    const int T = *Tp;
    const int hd = h * 128;
    const bool qg = isg[qrow] != 0;
    const size_t obase = (size_t)qrow * D_MODEL + hd + t;
    if (qrow >= T && !qg) {            // pad row: uniform softmax over all 2048
        ctx[obase] = (__bf16)(vmean[hd + t] * (1.0f / 2048.0f));
        return;
    }
    __shared__ float qv[128], ew[128];
    __shared__ int ci[128];
    __shared__ float redm[2], reds[2];
    __shared__ int ncs;
    qv[t] = qkv[(size_t)qrow * 3072 + hd + t];
    __syncthreads();
    const float scale = 0.088388347648318447f;   // 1/sqrt(128)

    if (!qg) {
        // local row: window ∪ out-of-window globals (all nonpad), <=97 cols
        int wl = qrow - 32; if (wl < 0) wl = 0;
        int wh = qrow + 32; if (wh > S_LEN - 1) wh = S_LEN - 1;
        if (t == 0) ncs = 0;
        __syncthreads();
        if (t <= wh - wl) {
            const int k = wl + t;
            if (k < T || isg[k]) { const int p = atomicAdd(&ncs, 1); ci[p] = k; }
        }
        const int ng = *ngcp;
        if (t < ng) {
            const int k = gcols[t];
            if (k < wl || k > wh) { const int p = atomicAdd(&ncs, 1); ci[p] = k; }
        }
        __syncthreads();
        const int nc = ncs;
        float s = -1e30f;
        const bool valid = t < nc;
        if (valid) {
            const float4* kr = (const float4*)(qkv + (size_t)ci[t] * 3072 + 1024 + hd);
            float d = 0.f;
            #pragma unroll 8
            for (int j = 0; j < 32; j++) {
                const float4 kk = kr[j];
                d += qv[4*j]*kk.x + qv[4*j+1]*kk.y + qv[4*j+2]*kk.z + qv[4*j+3]*kk.w;
            }
            s = d * scale;
        }
        const float M = blockRedMax<2>(s, redm);
        const float e = valid ? __expf(s - M) : 0.0f;
        ew[t] = e;
        const float l = blockRedSum<2>(e, reds);
        float a = 0.f;
        for (int j = 0; j < nc; j++) a += ew[j] * qkv[(size_t)ci[j] * 3072 + 2048 + hd + t];
        ctx[obase] = (__bf16)(a / l);
    } else {
        // global row: attends to all nonpad columns; online softmax over 16 chunks
        float m = -1e30f, l = 0.f, acc = 0.f;
        for (int base = 0; base < S_LEN; base += 128) {
            const int k = base + t;
            const bool valid = (k < T) || (isg[k] != 0);
            float s = -1e30f;
            if (valid) {
                const float4* kr = (const float4*)(qkv + (size_t)k * 3072 + 1024 + hd);
                float d = 0.f;
                #pragma unroll 8
                for (int j = 0; j < 32; j++) {
                    const float4 kk = kr[j];
                    d += qv[4*j]*kk.x + qv[4*j+1]*kk.y + qv[4*j+2]*kk.z + qv[4*j+3]*kk.w;
                }
                s = d * scale;
            }
            const float Mc = blockRedMax<2>(s, redm);
            const float nm = fmaxf(m, Mc);
            const float alpha = __expf(m - nm);   // m=-1e30,nm=-1e30 -> exp(0)=1, harmless (l=0,acc=0)
            const float e = valid ? __expf(s - nm) : 0.0f;
            ew[t] = e;
            const float Sc = blockRedSum<2>(e, reds);
            float a2 = 0.f;
            #pragma unroll 4
            for (int j = 0; j < 128; j++) a2 += ew[j] * qkv[(size_t)(base + j) * 3072 + 2048 + hd + t];
            acc = acc * alpha + a2;
            l = l * alpha + Sc;
            m = nm;
            __syncthreads();   // protect ew before next chunk overwrite
        }
        ctx[obase] = (__bf16)(acc / l);
    }
}

// x = LN(y + r); writes fp32 (xo) + bf16 (xb)
__global__ __launch_bounds__(256)
void ln_kernel(const float* __restrict__ y, const float* __restrict__ r,
               const float* __restrict__ g, const float* __restrict__ b,
               float* __restrict__ xo, __bf16* __restrict__ xb) {
    const int row = blockIdx.x, t = threadIdx.x;
    const float* yr = y + (size_t)row * D_MODEL;
    const float* rr = r + (size_t)row * D_MODEL;
    __shared__ float red[4];
    float v[4]; float s = 0.f;
    #pragma unroll
    for (int i = 0; i < 4; i++) { const int d = t + i * 256; v[i] = yr[d] + rr[d]; s += v[i]; }
    s = blockRedSum<4>(s, red);
    const float mu = s * (1.0f / 1024.0f);
    float vs = 0.f;
    #pragma unroll
    for (int i = 0; i < 4; i++) { const float dd = v[i] - mu; vs += dd * dd; }
    vs = blockRedSum<4>(vs, red);
    const float rstd = rsqrtf(vs * (1.0f / 1024.0f) + 1e-5f);
    #pragma unroll
    for (int i = 0; i < 4; i++) {
        const int d = t + i * 256;
        const float o = g[d] * (v[i] - mu) * rstd + b[d];
        xo[(size_t)row * D_MODEL + d] = o;
        xb[(size_t)row * D_MODEL + d] = (__bf16)o;
    }
}

extern "C" void kernel_launch(void* const* d_in, const int* in_sizes, int n_in,
                              void* d_out, int out_size, void* d_ws, size_t ws_size,
                              hipStream_t stream) {
    const int*   Tp   = (const int*)  d_in[0];
    const float* enc  = (const float*)d_in[1];
    const int*   gidx = (const int*)  d_in[2];
    const float* Wq   = (const float*)d_in[3];
    const float* Wk   = (const float*)d_in[4];
    const float* Wv   = (const float*)d_in[5];
    const float* Wo   = (const float*)d_in[6];
    const float* ln1g = (const float*)d_in[7];
    const float* ln1b = (const float*)d_in[8];
    const float* W1   = (const float*)d_in[9];
    const float* W2   = (const float*)d_in[10];
    const float* ln2g = (const float*)d_in[11];
    const float* ln2b = (const float*)d_in[12];

    char* p = (char*)d_ws;
    size_t off = 0;
    auto alloc = [&](size_t bytes) -> void* {
        void* q = p + off;
        off += (bytes + 255) & ~(size_t)255;
        return q;
    };
    float*  x     = (float*) alloc((size_t)S_LEN * D_MODEL * 4);
    __bf16* xb    = (__bf16*)alloc((size_t)S_LEN * D_MODEL * 2);
    float*  qkv   = (float*) alloc((size_t)S_LEN * 3072 * 4);
    __bf16* ctx   = (__bf16*)alloc((size_t)S_LEN * D_MODEL * 2);
    float*  g1    = (float*) alloc((size_t)S_LEN * D_MODEL * 4);
    __bf16* h1    = (__bf16*)alloc((size_t)S_LEN * D_FF * 2);
    __bf16* wT    = (__bf16*)alloc((size_t)3072 * 1024 * 2);
    float*  vmean = (float*) alloc(1024 * 4);
    int*    isg   = (int*)   alloc(S_LEN * 4);
    int*    gcols = (int*)   alloc(S_LEN * 4);
    int*    ngc   = (int*)   alloc(256);

    const dim3 tb(32, 8);

    init_x_kernel<<<S_LEN, 256, 0, stream>>>(enc, x, xb);
    mask_setup_kernel<<<1, 256, 0, stream>>>(gidx, isg, gcols, ngc);

    for (int l = 0; l < NLAYER; l++) {
        // --- QKV projection (fused N=3072) ---
        transpose_bf16_kernel<<<dim3(32, 32), tb, 0, stream>>>(Wq + (size_t)l * 1024 * 1024, wT,                1024, 1024);
        transpose_bf16_kernel<<<dim3(32, 32), tb, 0, stream>>>(Wk + (size_t)l * 1024 * 1024, wT + 1024 * 1024,  1024, 1024);
        transpose_bf16_kernel<<<dim3(32, 32), tb, 0, stream>>>(Wv + (size_t)l * 1024 * 1024, wT + 2048 * 1024,  1024, 1024);
        gemm_bt<0><<<dim3(24, 16), 256, 0, stream>>>(xb, wT, (void*)qkv, S_LEN, 3072, 1024);

        // --- attention ---
        zero_f_kernel<<<4, 256, 0, stream>>>(vmean, 1024);
        vmean_kernel<<<dim3(4, 16), 256, 0, stream>>>(qkv, vmean);
        attn_kernel<<<dim3(S_LEN, 8), 128, 0, stream>>>(qkv, Tp, isg, gcols, ngc, vmean, ctx);

        // --- output projection + LN1 ---
        transpose_bf16_kernel<<<dim3(32, 32), tb, 0, stream>>>(Wo + (size_t)l * 1024 * 1024, wT, 1024, 1024);
        gemm_bt<0><<<dim3(8, 16), 256, 0, stream>>>(ctx, wT, (void*)g1, S_LEN, 1024, 1024);
        ln_kernel<<<S_LEN, 256, 0, stream>>>(g1, x, ln1g + l * 1024, ln1b + l * 1024, x, xb);

        // --- FFN ---
        transpose_bf16_kernel<<<dim3(64, 32), tb, 0, stream>>>(W1 + (size_t)l * 1024 * 2048, wT, 1024, 2048);
        gemm_bt<1><<<dim3(16, 16), 256, 0, stream>>>(xb, wT, (void*)h1, S_LEN, 2048, 1024);   // relu -> bf16
        transpose_bf16_kernel<<<dim3(32, 64), tb, 0, stream>>>(W2 + (size_t)l * 2048 * 1024, wT, 2048, 1024);
        gemm_bt<0><<<dim3(8, 16), 256, 0, stream>>>(h1, wT, (void*)g1, S_LEN, 1024, 2048);
        float* xout = (l == NLAYER - 1) ? (float*)d_out : x;
        ln_kernel<<<S_LEN, 256, 0, stream>>>(g1, x, ln2g + l * 1024, ln2b + l * 1024, xout, xb);
    }
}

// Round 2
// 1210.294 us; speedup vs baseline: 2.0368x; 2.0368x over previous
//
#include <hip/hip_runtime.h>
#include <cstdint>
#include <cstddef>

#define S_LEN  2048
#define D_MODEL 1024
#define D_FF   2048
#define NLAYER 4
// H=8, DK=128, WINDOW=64 (half=32)

typedef float  f32x4  __attribute__((ext_vector_type(4)));
typedef __bf16 bf16x8 __attribute__((ext_vector_type(8)));

#define ATT_SCALE 0.08838834764831845f   // 1/sqrt(128)

__device__ __forceinline__ void async_copy16(const void* g, void* s) {
    __builtin_amdgcn_global_load_lds((const __attribute__((address_space(1))) void*)g,
                                     (__attribute__((address_space(3))) void*)s, 16, 0, 0);
}

template<int NW>
__device__ __forceinline__ float blockRedSum(float v, float* red) {
    #pragma unroll
    for (int off = 32; off > 0; off >>= 1) v += __shfl_down(v, off);
    const int t = threadIdx.x;
    if ((t & 63) == 0) red[t >> 6] = v;
    __syncthreads();
    float r = red[0];
    #pragma unroll
    for (int i = 1; i < NW; i++) r += red[i];
    __syncthreads();
    return r;
}

// x = 2*enc + sinusoidal_pe; writes fp32 + bf16
__global__ __launch_bounds__(256)
void init_x_kernel(const float* __restrict__ enc, float* __restrict__ x, __bf16* __restrict__ xb) {
    const int s = blockIdx.x, t = threadIdx.x;
    #pragma unroll
    for (int i = 0; i < 4; i++) {
        const int d = t + i * 256;
        const float freq = expf(-(float)(d & ~1) * (9.210340371976184f / 1024.0f));
        const float ang = (float)s * freq;
        const float pe = (d & 1) ? cosf(ang) : sinf(ang);
        const float v = 2.0f * enc[(size_t)s * D_MODEL + d] + pe;
        x[(size_t)s * D_MODEL + d] = v;
        xb[(size_t)s * D_MODEL + d] = (__bf16)v;
    }
}

// is_global flags + compacted global column list
__global__ void mask_setup_kernel(const int* __restrict__ gidx, int* __restrict__ isg,
                                  int* __restrict__ gcols, int* __restrict__ ngc) {
    const int t = threadIdx.x;
    for (int s = t; s < S_LEN; s += 256) {
        int f = 0;
        for (int i = 0; i < 32; i++) {
            const int g = gidx[i] / 15;   // gidx >= 0
            if (g >= 0 && g < S_LEN && g == s) f = 1;
        }
        isg[s] = f;
    }
    __syncthreads();
    if (t == 0) {
        int n = 0;
        for (int s = 0; s < S_LEN; s++) if (isg[s]) gcols[n++] = s;
        *ngc = n;
    }
}

// W fp32 [K][N] -> Wt bf16 [N][K]
__global__ __launch_bounds__(256)
void transpose_bf16_kernel(const float* __restrict__ in, __bf16* __restrict__ out, int K, int N) {
    __shared__ float tile[32][33];
    const int tx = threadIdx.x, ty = threadIdx.y;
    const int n0 = blockIdx.x * 32, k0 = blockIdx.y * 32;
    #pragma unroll
    for (int i = ty; i < 32; i += 8)
        tile[i][tx] = in[(size_t)(k0 + i) * N + n0 + tx];
    __syncthreads();
    #pragma unroll
    for (int i = ty; i < 32; i += 8)
        out[(size_t)(n0 + i) * K + k0 + tx] = (__bf16)tile[tx][i];
}

// C[M][N] = A[M][K] * Bt[N][K]^T ; EPI 0: fp32 out, 1: relu->bf16 out
template<int EPI>
__global__ __launch_bounds__(256)
void gemm_bt(const __bf16* __restrict__ A, const __bf16* __restrict__ Bt,
             void* __restrict__ Cv, int M, int N, int K) {
    __shared__ __bf16 As[128 * 32];
    __shared__ __bf16 Bs[128 * 32];
    const int t = threadIdx.x;
    const int w = t >> 6, l = t & 63;
    const int l15 = l & 15, q4 = l >> 4;
    const int wr = w >> 1, wc = w & 1;
    const int m0 = blockIdx.y * 128, n0 = blockIdx.x * 128;

    const int row = t >> 2;          // 0..63
    const int kc  = (t & 3) * 8;     // element offset in K-tile
    const __bf16* ag0 = A  + (size_t)(m0 + row) * K + kc;
    const __bf16* ag1 = A  + (size_t)(m0 + row + 64) * K + kc;
    const __bf16* bg0 = Bt + (size_t)(n0 + row) * K + kc;
    const __bf16* bg1 = Bt + (size_t)(n0 + row + 64) * K + kc;
    __bf16* asw = As + w * 512;      // wave-uniform LDS base
    __bf16* bsw = Bs + w * 512;

    const int aoff = (wr * 64 + l15) * 32 + q4 * 8;
    const int boff = (wc * 64 + l15) * 32 + q4 * 8;

    f32x4 acc[4][4];
    #pragma unroll
    for (int i = 0; i < 4; i++)
        #pragma unroll
        for (int j = 0; j < 4; j++) acc[i][j] = (f32x4){0.f, 0.f, 0.f, 0.f};

    for (int k0 = 0; k0 < K; k0 += 32) {
        async_copy16(ag0 + k0, asw);
        async_copy16(ag1 + k0, asw + 2048);
        async_copy16(bg0 + k0, bsw);
        async_copy16(bg1 + k0, bsw + 2048);
        __syncthreads();
        bf16x8 af[4], bfr[4];
        #pragma unroll
        for (int i = 0; i < 4; i++) af[i]  = *(const bf16x8*)(As + aoff + i * 512);
        #pragma unroll
        for (int j = 0; j < 4; j++) bfr[j] = *(const bf16x8*)(Bs + boff + j * 512);
        #pragma unroll
        for (int i = 0; i < 4; i++)
            #pragma unroll
            for (int j = 0; j < 4; j++)
                acc[i][j] = __builtin_amdgcn_mfma_f32_16x16x32_bf16(af[i], bfr[j], acc[i][j], 0, 0, 0);
        __syncthreads();
    }

    const int r0 = m0 + wr * 64 + q4 * 4;
    const int c0 = n0 + wc * 64 + l15;
    if (EPI == 0) {
        float* C = (float*)Cv;
        #pragma unroll
        for (int i = 0; i < 4; i++)
            #pragma unroll
            for (int j = 0; j < 4; j++)
                #pragma unroll
                for (int r = 0; r < 4; r++)
                    C[(size_t)(r0 + i * 16 + r) * N + c0 + j * 16] = acc[i][j][r];
    } else {
        __bf16* C = (__bf16*)Cv;
        #pragma unroll
        for (int i = 0; i < 4; i++)
            #pragma unroll
            for (int j = 0; j < 4; j++)
                #pragma unroll
                for (int r = 0; r < 4; r++)
                    C[(size_t)(r0 + i * 16 + r) * N + c0 + j * 16] = (__bf16)fmaxf(acc[i][j][r], 0.0f);
    }
}

__global__ void zero_f_kernel(float* p, int n) {
    const int i = blockIdx.x * 256 + threadIdx.x;
    if (i < n) p[i] = 0.0f;
}

// column sums of V (qkv cols 2048..3071) -> vmean (SUM over all 2048 rows)
__global__ __launch_bounds__(256)
void vmean_kernel(const float* __restrict__ qkv, float* __restrict__ vmean) {
    const int d = blockIdx.x * 256 + threadIdx.x;      // 0..1023
    const int s0 = blockIdx.y * 128;
    float s = 0.f;
    for (int i = 0; i < 128; i++) s += qkv[(size_t)(s0 + i) * 3072 + 2048 + d];
    atomicAdd(&vmean[d], s);
}

// ---------------- MFMA attention ----------------
// local rows: block = (32-row q-tile, head). Column set = window ∪ out-of-window
// globals (<=128 cols). Pad rows get vmean/2048. Global rows skipped here.
__global__ __launch_bounds__(256)
void attn_local(const float* __restrict__ qkv, const int* __restrict__ Tp,
                const int* __restrict__ isg, const int* __restrict__ gcols,
                const int* __restrict__ ngcp, const float* __restrict__ vmean,
                __bf16* __restrict__ ctx) {
    const int qt0 = blockIdx.x * 32, h = blockIdx.y, hd = h * 128;
    const int t = threadIdx.x;
    __shared__ __bf16 Qs[32 * 136];
    __shared__ __bf16 Ks[128 * 136];
    __shared__ __bf16 Vs[128 * 136];
    __shared__ __bf16 Ps[32 * 136];
    __shared__ float  Ss[32 * 129];
    __shared__ int cix[128], cgf[128], rtype[32];
    __shared__ int ncs;
    const int T = *Tp, ng = *ngcp;
    const int wl = max(qt0 - 32, 0), wh = min(qt0 + 63, S_LEN - 1);
    if (t == 0) ncs = 0;
    if (t < 32) { const int qr = qt0 + t; rtype[t] = isg[qr] ? 1 : (qr < T ? 0 : 2); }
    __syncthreads();
    if (t <= wh - wl) {
        const int c = wl + t, gf = isg[c];
        if (c < T || gf) { const int p = atomicAdd(&ncs, 1); cix[p] = c; cgf[p] = gf; }
    }
    if (t < ng) {
        const int c = gcols[t];
        if (c < wl || c > wh) { const int p = atomicAdd(&ncs, 1); cix[p] = c; cgf[p] = 1; }
    }
    // stage Q (independent of col list)
    {
        const int r = t >> 3, d0 = (t & 7) * 16;
        const float4* src = (const float4*)(qkv + (size_t)(qt0 + r) * 3072 + hd + d0);
        #pragma unroll
        for (int i = 0; i < 4; i++) {
            const float4 v = src[i];
            __bf16* q = &Qs[r * 136 + d0 + i * 4];
            q[0] = (__bf16)v.x; q[1] = (__bf16)v.y; q[2] = (__bf16)v.z; q[3] = (__bf16)v.w;
        }
    }
    __syncthreads();
    const int nc = ncs;
    if (nc + t < 128) { cix[nc + t] = -1; cgf[nc + t] = 0; }   // sentinels
    // stage K/V (j >= nc -> zero fill; don't read sentinel cix, it races)
    {
        const int j = t >> 1, d0 = (t & 1) * 64;
        const int ci = (j < nc) ? cix[j] : -1;
        if (ci >= 0) {
            const float4* kp = (const float4*)(qkv + (size_t)ci * 3072 + 1024 + hd + d0);
            const float4* vp = (const float4*)(qkv + (size_t)ci * 3072 + 2048 + hd + d0);
            #pragma unroll
            for (int i = 0; i < 16; i++) {
                const float4 kv = kp[i]; const float4 vv = vp[i];
                __bf16* kq = &Ks[j * 136 + d0 + i * 4];
                __bf16* vq = &Vs[j * 136 + d0 + i * 4];
                kq[0] = (__bf16)kv.x; kq[1] = (__bf16)kv.y; kq[2] = (__bf16)kv.z; kq[3] = (__bf16)kv.w;
                vq[0] = (__bf16)vv.x; vq[1] = (__bf16)vv.y; vq[2] = (__bf16)vv.z; vq[3] = (__bf16)vv.w;
            }
        } else {
            #pragma unroll
            for (int i = 0; i < 16; i++) {
                __bf16* kq = &Ks[j * 136 + d0 + i * 4];
                __bf16* vq = &Vs[j * 136 + d0 + i * 4];
                kq[0] = kq[1] = kq[2] = kq[3] = (__bf16)0.f;
                vq[0] = vq[1] = vq[2] = vq[3] = (__bf16)0.f;
            }
        }
    }
    __syncthreads();

    const int l = t & 63, w = t >> 6;
    const int l15 = l & 15, q4 = l >> 4;
    const int nb = w * 32;
    // S = Q K^T  (M=32, N=128, K=128)
    {
        f32x4 sacc[2][2];
        #pragma unroll
        for (int i = 0; i < 2; i++)
            #pragma unroll
            for (int j = 0; j < 2; j++) sacc[i][j] = (f32x4){0.f, 0.f, 0.f, 0.f};
        #pragma unroll
        for (int kk = 0; kk < 4; kk++) {
            const int k0 = kk * 32;
            bf16x8 af[2], bk[2];
            af[0] = *(const bf16x8*)&Qs[l15 * 136 + k0 + q4 * 8];
            af[1] = *(const bf16x8*)&Qs[(16 + l15) * 136 + k0 + q4 * 8];
            bk[0] = *(const bf16x8*)&Ks[(nb + l15) * 136 + k0 + q4 * 8];
            bk[1] = *(const bf16x8*)&Ks[(nb + 16 + l15) * 136 + k0 + q4 * 8];
            #pragma unroll
            for (int m2 = 0; m2 < 2; m2++)
                #pragma unroll
                for (int n2 = 0; n2 < 2; n2++)
                    sacc[m2][n2] = __builtin_amdgcn_mfma_f32_16x16x32_bf16(af[m2], bk[n2], sacc[m2][n2], 0, 0, 0);
        }
        #pragma unroll
        for (int m2 = 0; m2 < 2; m2++)
            #pragma unroll
            for (int n2 = 0; n2 < 2; n2++)
                #pragma unroll
                for (int r = 0; r < 4; r++) {
                    const int row = m2 * 16 + q4 * 4 + r;
                    const int col = nb + n2 * 16 + l15;
                    const int c = cix[col];
                    const int dd = qt0 + row - c;
                    const bool ok = (c >= 0) && (((unsigned)(dd + 32) <= 64u) || cgf[col]);
                    Ss[row * 129 + col] = ok ? sacc[m2][n2][r] * ATT_SCALE : -1e30f;
                }
    }
    __syncthreads();
    // softmax (normalized) -> Ps bf16
    {
        const int r = t >> 3, i = t & 7;
        float mx = -1e30f;
        for (int c = i; c < 128; c += 8) mx = fmaxf(mx, Ss[r * 129 + c]);
        #pragma unroll
        for (int off = 4; off > 0; off >>= 1) mx = fmaxf(mx, __shfl_down(mx, off, 8));
        mx = __shfl(mx, 0, 8);
        float sm = 0.f;
        for (int c = i; c < 128; c += 8) {
            const float s = Ss[r * 129 + c];
            const float p = (s > -1e29f) ? __expf(s - mx) : 0.f;
            Ss[r * 129 + c] = p;
            sm += p;
        }
        #pragma unroll
        for (int off = 4; off > 0; off >>= 1) sm += __shfl_down(sm, off, 8);
        sm = __shfl(sm, 0, 8);
        const float rl = 1.0f / fmaxf(sm, 1e-30f);
        for (int c = i; c < 128; c += 8) Ps[r * 136 + c] = (__bf16)(Ss[r * 129 + c] * rl);
    }
    __syncthreads();
    // O = P V  (M=32 rows, N=128 dims, K=128 cols)
    {
        f32x4 oacc[2][2];
        #pragma unroll
        for (int i = 0; i < 2; i++)
            #pragma unroll
            for (int j = 0; j < 2; j++) oacc[i][j] = (f32x4){0.f, 0.f, 0.f, 0.f};
        #pragma unroll
        for (int kk = 0; kk < 4; kk++) {
            const int k0 = kk * 32;
            bf16x8 ap[2], bv[2];
            ap[0] = *(const bf16x8*)&Ps[l15 * 136 + k0 + q4 * 8];
            ap[1] = *(const bf16x8*)&Ps[(16 + l15) * 136 + k0 + q4 * 8];
            #pragma unroll
            for (int n2 = 0; n2 < 2; n2++) {
                const int dimn = nb + n2 * 16 + l15;
                #pragma unroll
                for (int jj = 0; jj < 8; jj++)
                    bv[n2][jj] = Vs[(k0 + q4 * 8 + jj) * 136 + dimn];
            }
            #pragma unroll
            for (int m2 = 0; m2 < 2; m2++)
                #pragma unroll
                for (int n2 = 0; n2 < 2; n2++)
                    oacc[m2][n2] = __builtin_amdgcn_mfma_f32_16x16x32_bf16(ap[m2], bv[n2], oacc[m2][n2], 0, 0, 0);
        }
        #pragma unroll
        for (int m2 = 0; m2 < 2; m2++)
            #pragma unroll
            for (int n2 = 0; n2 < 2; n2++)
                #pragma unroll
                for (int r = 0; r < 4; r++) {
                    const int row = m2 * 16 + q4 * 4 + r;
                    const int dim = nb + n2 * 16 + l15;
                    const int rt = rtype[row];
                    const size_t o = (size_t)(qt0 + row) * D_MODEL + hd + dim;
                    if (rt == 0)      ctx[o] = (__bf16)oacc[m2][n2][r];
                    else if (rt == 2) ctx[o] = (__bf16)(vmean[hd + dim] * (1.0f / 2048.0f));
                }
    }
}

// global rows, partial flash over one 128-col chunk. block = (chunk, head).
__global__ __launch_bounds__(256)
void attn_gpart(const float* __restrict__ qkv, const int* __restrict__ Tp,
                const int* __restrict__ isg, const int* __restrict__ gcols,
                const int* __restrict__ ngcp, float* __restrict__ Og,
                float* __restrict__ mg, float* __restrict__ lg) {
    const int cb = blockIdx.x, h = blockIdx.y, hd = h * 128, c0 = cb * 128;
    const int t = threadIdx.x;
    const int ng = *ngcp, T = *Tp;
    if (ng == 0) return;
    __shared__ __bf16 Qs[32 * 136];
    __shared__ __bf16 Ks[128 * 136];
    __shared__ __bf16 Vs[128 * 136];
    __shared__ __bf16 Ps[32 * 136];
    __shared__ float  Ss[32 * 129];
    __shared__ int vf[128];
    // stage Q (gathered global rows)
    {
        const int r = t >> 3, d0 = (t & 7) * 16;
        if (r < ng) {
            const float4* src = (const float4*)(qkv + (size_t)gcols[r] * 3072 + hd + d0);
            #pragma unroll
            for (int i = 0; i < 4; i++) {
                const float4 v = src[i];
                __bf16* q = &Qs[r * 136 + d0 + i * 4];
                q[0] = (__bf16)v.x; q[1] = (__bf16)v.y; q[2] = (__bf16)v.z; q[3] = (__bf16)v.w;
            }
        } else {
            #pragma unroll
            for (int i = 0; i < 4; i++) {
                __bf16* q = &Qs[r * 136 + d0 + i * 4];
                q[0] = q[1] = q[2] = q[3] = (__bf16)0.f;
            }
        }
    }
    if (t < 128) { const int c = c0 + t; vf[t] = (c < T || isg[c]) ? 1 : 0; }
    // stage K/V chunk rows
    {
        const int j = t >> 1, d0 = (t & 1) * 64;
        const int ci = c0 + j;
        const float4* kp = (const float4*)(qkv + (size_t)ci * 3072 + 1024 + hd + d0);
        const float4* vp = (const float4*)(qkv + (size_t)ci * 3072 + 2048 + hd + d0);
        #pragma unroll
        for (int i = 0; i < 16; i++) {
            const float4 kv = kp[i]; const float4 vv = vp[i];
            __bf16* kq = &Ks[j * 136 + d0 + i * 4];
            __bf16* vq = &Vs[j * 136 + d0 + i * 4];
            kq[0] = (__bf16)kv.x; kq[1] = (__bf16)kv.y; kq[2] = (__bf16)kv.z; kq[3] = (__bf16)kv.w;
            vq[0] = (__bf16)vv.x; vq[1] = (__bf16)vv.y; vq[2] = (__bf16)vv.z; vq[3] = (__bf16)vv.w;
        }
    }
    __syncthreads();

    const int l = t & 63, w = t >> 6;
    const int l15 = l & 15, q4 = l >> 4;
    const int nb = w * 32;
    {
        f32x4 sacc[2][2];
        #pragma unroll
        for (int i = 0; i < 2; i++)
            #pragma unroll
            for (int j = 0; j < 2; j++) sacc[i][j] = (f32x4){0.f, 0.f, 0.f, 0.f};
        #pragma unroll
        for (int kk = 0; kk < 4; kk++) {
            const int k0 = kk * 32;
            bf16x8 af[2], bk[2];
            af[0] = *(const bf16x8*)&Qs[l15 * 136 + k0 + q4 * 8];
            af[1] = *(const bf16x8*)&Qs[(16 + l15) * 136 + k0 + q4 * 8];
            bk[0] = *(const bf16x8*)&Ks[(nb + l15) * 136 + k0 + q4 * 8];
            bk[1] = *(const bf16x8*)&Ks[(nb + 16 + l15) * 136 + k0 + q4 * 8];
            #pragma unroll
            for (int m2 = 0; m2 < 2; m2++)
                #pragma unroll
                for (int n2 = 0; n2 < 2; n2++)
                    sacc[m2][n2] = __builtin_amdgcn_mfma_f32_16x16x32_bf16(af[m2], bk[n2], sacc[m2][n2], 0, 0, 0);
        }
        #pragma unroll
        for (int m2 = 0; m2 < 2; m2++)
            #pragma unroll
            for (int n2 = 0; n2 < 2; n2++)
                #pragma unroll
                for (int r = 0; r < 4; r++) {
                    const int row = m2 * 16 + q4 * 4 + r;
                    const int col = nb + n2 * 16 + l15;
                    Ss[row * 129 + col] = vf[col] ? sacc[m2][n2][r] * ATT_SCALE : -1e30f;
                }
    }
    __syncthreads();
    // partial softmax: p = exp(s - m_c) (UNnormalized); save m_c, l_c
    {
        const int r = t >> 3, i = t & 7;
        float mx = -1e30f;
        for (int c = i; c < 128; c += 8) mx = fmaxf(mx, Ss[r * 129 + c]);
        #pragma unroll
        for (int off = 4; off > 0; off >>= 1) mx = fmaxf(mx, __shfl_down(mx, off, 8));
        mx = __shfl(mx, 0, 8);
        float sm = 0.f;
        for (int c = i; c < 128; c += 8) {
            const float s = Ss[r * 129 + c];
            const float p = (s > -1e29f) ? __expf(s - mx) : 0.f;
            Ps[r * 136 + c] = (__bf16)p;
            sm += p;
        }
        #pragma unroll
        for (int off = 4; off > 0; off >>= 1) sm += __shfl_down(sm, off, 8);
        if (i == 0) { mg[(h * 16 + cb) * 32 + r] = mx; lg[(h * 16 + cb) * 32 + r] = sm; }
    }
    __syncthreads();
    // O_c = P V
    {
        f32x4 oacc[2][2];
        #pragma unroll
        for (int i = 0; i < 2; i++)
            #pragma unroll
            for (int j = 0; j < 2; j++) oacc[i][j] = (f32x4){0.f, 0.f, 0.f, 0.f};
        #pragma unroll
        for (int kk = 0; kk < 4; kk++) {
            const int k0 = kk * 32;
            bf16x8 ap[2], bv[2];
            ap[0] = *(const bf16x8*)&Ps[l15 * 136 + k0 + q4 * 8];
            ap[1] = *(const bf16x8*)&Ps[(16 + l15) * 136 + k0 + q4 * 8];
            #pragma unroll
            for (int n2 = 0; n2 < 2; n2++) {
                const int dimn = nb + n2 * 16 + l15;
                #pragma unroll
                for (int jj = 0; jj < 8; jj++)
                    bv[n2][jj] = Vs[(k0 + q4 * 8 + jj) * 136 + dimn];
            }
            #pragma unroll
            for (int m2 = 0; m2 < 2; m2++)
                #pragma unroll
                for (int n2 = 0; n2 < 2; n2++)
                    oacc[m2][n2] = __builtin_amdgcn_mfma_f32_16x16x32_bf16(ap[m2], bv[n2], oacc[m2][n2], 0, 0, 0);
        }
        #pragma unroll
        for (int m2 = 0; m2 < 2; m2++)
            #pragma unroll
            for (int n2 = 0; n2 < 2; n2++)
                #pragma unroll
                for (int r = 0; r < 4; r++) {
                    const int row = m2 * 16 + q4 * 4 + r;
                    const int dim = nb + n2 * 16 + l15;
                    Og[((size_t)(h * 16 + cb) * 32 + row) * 128 + dim] = oacc[m2][n2][r];
                }
    }
}

// combine the 16 chunks for global rows
__global__ __launch_bounds__(256)
void attn_gcomb(const int* __restrict__ gcols, const int* __restrict__ ngcp,
                const float* __restrict__ Og, const float* __restrict__ mg,
                const float* __restrict__ lg, __bf16* __restrict__ ctx) {
    const int h = blockIdx.x, hd = h * 128, t = threadIdx.x;
    const int ng = *ngcp;
    const int r = t >> 3, i = t & 7;
    if (r >= ng) return;
    float M = -1e30f;
    #pragma unroll
    for (int cb = 0; cb < 16; cb++) M = fmaxf(M, mg[(h * 16 + cb) * 32 + r]);
    float e[16], L = 0.f;
    #pragma unroll
    for (int cb = 0; cb < 16; cb++) {
        e[cb] = __expf(mg[(h * 16 + cb) * 32 + r] - M);
        L += e[cb] * lg[(h * 16 + cb) * 32 + r];
    }
    const float rL = 1.0f / fmaxf(L, 1e-30f);
    const int grow = gcols[r];
    for (int d = i; d < 128; d += 8) {
        float o = 0.f;
        #pragma unroll
        for (int cb = 0; cb < 16; cb++)
            o += e[cb] * Og[((size_t)(h * 16 + cb) * 32 + r) * 128 + d];
        ctx[(size_t)grow * D_MODEL + hd + d] = (__bf16)(o * rL);
    }
}

// x = LN(y + r); writes fp32 (xo) + bf16 (xb)
__global__ __launch_bounds__(256)
void ln_kernel(const float* __restrict__ y, const float* __restrict__ r,
               const float* __restrict__ g, const float* __restrict__ b,
               float* __restrict__ xo, __bf16* __restrict__ xb) {
    const int row = blockIdx.x, t = threadIdx.x;
    const float* yr = y + (size_t)row * D_MODEL;
    const float* rr = r + (size_t)row * D_MODEL;
    __shared__ float red[4];
    float v[4]; float s = 0.f;
    #pragma unroll
    for (int i = 0; i < 4; i++) { const int d = t + i * 256; v[i] = yr[d] + rr[d]; s += v[i]; }
    s = blockRedSum<4>(s, red);
    const float mu = s * (1.0f / 1024.0f);
    float vs = 0.f;
    #pragma unroll
    for (int i = 0; i < 4; i++) { const float dd = v[i] - mu; vs += dd * dd; }
    vs = blockRedSum<4>(vs, red);
    const float rstd = rsqrtf(vs * (1.0f / 1024.0f) + 1e-5f);
    #pragma unroll
    for (int i = 0; i < 4; i++) {
        const int d = t + i * 256;
        const float o = g[d] * (v[i] - mu) * rstd + b[d];
        xo[(size_t)row * D_MODEL + d] = o;
        xb[(size_t)row * D_MODEL + d] = (__bf16)o;
    }
}

extern "C" void kernel_launch(void* const* d_in, const int* in_sizes, int n_in,
                              void* d_out, int out_size, void* d_ws, size_t ws_size,
                              hipStream_t stream) {
    const int*   Tp   = (const int*)  d_in[0];
    const float* enc  = (const float*)d_in[1];
    const int*   gidx = (const int*)  d_in[2];
    const float* Wq   = (const float*)d_in[3];
    const float* Wk   = (const float*)d_in[4];
    const float* Wv   = (const float*)d_in[5];
    const float* Wo   = (const float*)d_in[6];
    const float* ln1g = (const float*)d_in[7];
    const float* ln1b = (const float*)d_in[8];
    const float* W1   = (const float*)d_in[9];
    const float* W2   = (const float*)d_in[10];
    const float* ln2g = (const float*)d_in[11];
    const float* ln2b = (const float*)d_in[12];

    char* p = (char*)d_ws;
    size_t off = 0;
    auto alloc = [&](size_t bytes) -> void* {
        void* q = p + off;
        off += (bytes + 255) & ~(size_t)255;
        return q;
    };
    float*  x     = (float*) alloc((size_t)S_LEN * D_MODEL * 4);
    __bf16* xb    = (__bf16*)alloc((size_t)S_LEN * D_MODEL * 2);
    float*  qkv   = (float*) alloc((size_t)S_LEN * 3072 * 4);
    __bf16* ctx   = (__bf16*)alloc((size_t)S_LEN * D_MODEL * 2);
    float*  g1    = (float*) alloc((size_t)S_LEN * D_MODEL * 4);
    __bf16* h1    = (__bf16*)alloc((size_t)S_LEN * D_FF * 2);
    __bf16* wT    = (__bf16*)alloc((size_t)3072 * 1024 * 2);
    float*  vmean = (float*) alloc(1024 * 4);
    int*    isg   = (int*)   alloc(S_LEN * 4);
    int*    gcols = (int*)   alloc(S_LEN * 4);
    int*    ngc   = (int*)   alloc(256);
    float*  Og    = (float*) alloc((size_t)8 * 16 * 32 * 128 * 4);
    float*  mgb   = (float*) alloc(8 * 16 * 32 * 4);
    float*  lgb   = (float*) alloc(8 * 16 * 32 * 4);

    const dim3 tb(32, 8);

    init_x_kernel<<<S_LEN, 256, 0, stream>>>(enc, x, xb);
    mask_setup_kernel<<<1, 256, 0, stream>>>(gidx, isg, gcols, ngc);

    for (int l = 0; l < NLAYER; l++) {
        // --- QKV projection (fused N=3072) ---
        transpose_bf16_kernel<<<dim3(32, 32), tb, 0, stream>>>(Wq + (size_t)l * 1024 * 1024, wT,                1024, 1024);
        transpose_bf16_kernel<<<dim3(32, 32), tb, 0, stream>>>(Wk + (size_t)l * 1024 * 1024, wT + 1024 * 1024,  1024, 1024);
        transpose_bf16_kernel<<<dim3(32, 32), tb, 0, stream>>>(Wv + (size_t)l * 1024 * 1024, wT + 2048 * 1024,  1024, 1024);
        gemm_bt<0><<<dim3(24, 16), 256, 0, stream>>>(xb, wT, (void*)qkv, S_LEN, 3072, 1024);

        // --- attention (MFMA, local/global/pad split) ---
        zero_f_kernel<<<4, 256, 0, stream>>>(vmean, 1024);
        vmean_kernel<<<dim3(4, 16), 256, 0, stream>>>(qkv, vmean);
        attn_local<<<dim3(64, 8), 256, 0, stream>>>(qkv, Tp, isg, gcols, ngc, vmean, ctx);
        attn_gpart<<<dim3(16, 8), 256, 0, stream>>>(qkv, Tp, isg, gcols, ngc, Og, mgb, lgb);
        attn_gcomb<<<8, 256, 0, stream>>>(gcols, ngc, Og, mgb, lgb, ctx);

        // --- output projection + LN1 ---
        transpose_bf16_kernel<<<dim3(32, 32), tb, 0, stream>>>(Wo + (size_t)l * 1024 * 1024, wT, 1024, 1024);
        gemm_bt<0><<<dim3(8, 16), 256, 0, stream>>>(ctx, wT, (void*)g1, S_LEN, 1024, 1024);
        ln_kernel<<<S_LEN, 256, 0, stream>>>(g1, x, ln1g + l * 1024, ln1b + l * 1024, x, xb);

        // --- FFN ---
        transpose_bf16_kernel<<<dim3(64, 32), tb, 0, stream>>>(W1 + (size_t)l * 1024 * 2048, wT, 1024, 2048);
        gemm_bt<1><<<dim3(16, 16), 256, 0, stream>>>(xb, wT, (void*)h1, S_LEN, 2048, 1024);   // relu -> bf16
        transpose_bf16_kernel<<<dim3(32, 64), tb, 0, stream>>>(W2 + (size_t)l * 2048 * 1024, wT, 2048, 1024);
        gemm_bt<0><<<dim3(8, 16), 256, 0, stream>>>(h1, wT, (void*)g1, S_LEN, 1024, 2048);
        float* xout = (l == NLAYER - 1) ? (float*)d_out : x;
        ln_kernel<<<S_LEN, 256, 0, stream>>>(g1, x, ln2g + l * 1024, ln2b + l * 1024, xout, xb);
    }
}

// Round 3
// 1014.772 us; speedup vs baseline: 2.4292x; 1.1927x over previous
//
#include <hip/hip_runtime.h>
#include <cstdint>
#include <cstddef>

#define S_LEN  2048
#define D_MODEL 1024
#define D_FF   2048
#define NLAYER 4
// H=8, DK=128, WINDOW=64 (half=32)

typedef float  f32x4  __attribute__((ext_vector_type(4)));
typedef __bf16 bf16x8 __attribute__((ext_vector_type(8)));

#define ATT_SCALE 0.08838834764831845f   // 1/sqrt(128)

__device__ __forceinline__ void async_copy16(const void* g, void* s) {
    __builtin_amdgcn_global_load_lds((const __attribute__((address_space(1))) void*)g,
                                     (__attribute__((address_space(3))) void*)s, 16, 0, 0);
}

template<int NW>
__device__ __forceinline__ float blockRedSum(float v, float* red) {
    #pragma unroll
    for (int off = 32; off > 0; off >>= 1) v += __shfl_down(v, off);
    const int t = threadIdx.x;
    if ((t & 63) == 0) red[t >> 6] = v;
    __syncthreads();
    float r = red[0];
    #pragma unroll
    for (int i = 1; i < NW; i++) r += red[i];
    __syncthreads();
    return r;
}

// x = 2*enc + sinusoidal_pe; writes fp32 + bf16
__global__ __launch_bounds__(256)
void init_x_kernel(const float* __restrict__ enc, float* __restrict__ x, __bf16* __restrict__ xb) {
    const int s = blockIdx.x, t = threadIdx.x;
    #pragma unroll
    for (int i = 0; i < 4; i++) {
        const int d = t + i * 256;
        const float freq = expf(-(float)(d & ~1) * (9.210340371976184f / 1024.0f));
        const float ang = (float)s * freq;
        const float pe = (d & 1) ? cosf(ang) : sinf(ang);
        const float v = 2.0f * enc[(size_t)s * D_MODEL + d] + pe;
        x[(size_t)s * D_MODEL + d] = v;
        xb[(size_t)s * D_MODEL + d] = (__bf16)v;
    }
}

// is_global flags + compacted (unordered, deduped) global column list — all in LDS
__global__ __launch_bounds__(1024)
void mask_setup_kernel(const int* __restrict__ gidx, int* __restrict__ isg,
                       int* __restrict__ gcols, int* __restrict__ ngc) {
    __shared__ int gsh[32];
    __shared__ int cnt;
    const int t = threadIdx.x;
    if (t < 32) {
        const int g = gidx[t] / 15;      // gidx >= 0, g in [0, 1800)
        gsh[t] = (g >= 0 && g < S_LEN) ? g : -1;
    }
    if (t == 0) cnt = 0;
    __syncthreads();
    #pragma unroll
    for (int i = 0; i < 2; i++) {
        const int s = t + i * 1024;
        int f = 0;
        #pragma unroll
        for (int j = 0; j < 32; j++) f |= (gsh[j] == s) ? 1 : 0;
        isg[s] = f;
        if (f) { const int p = atomicAdd(&cnt, 1); gcols[p] = s; }
    }
    __syncthreads();
    if (t == 0) *ngc = cnt;
}

// All 6 weight transposes of one layer in a single dispatch.
// fp32 [K][N] -> bf16 [N][K]. Arena layout (elements):
//   WqT 0..1M, WkT 1M..2M, WvT 2M..3M, WoT 3M..4M, W1T 4M..6M, W2T 6M..8M
__global__ __launch_bounds__(256)
void transpose_all_kernel(const float* __restrict__ Wq, const float* __restrict__ Wk,
                          const float* __restrict__ Wv, const float* __restrict__ Wo,
                          const float* __restrict__ W1, const float* __restrict__ W2,
                          __bf16* __restrict__ out) {
    int bid = blockIdx.x;
    const float* in; __bf16* o; int K, N, r;
    if (bid < 4096) {                       // four 1024x1024 mats, 1024 tiles each
        const int m = bid >> 10; r = bid & 1023; K = 1024; N = 1024;
        in = (m == 0) ? Wq : (m == 1) ? Wk : (m == 2) ? Wv : Wo;
        o  = out + (size_t)m * 1024 * 1024;
    } else {
        bid -= 4096;
        const int m = bid >> 11; r = bid & 2047;
        if (m == 0) { in = W1; K = 1024; N = 2048; o = out + (size_t)4 * 1024 * 1024; }
        else        { in = W2; K = 2048; N = 1024; o = out + (size_t)6 * 1024 * 1024; }
    }
    const int ntx = N >> 5;
    const int n0 = (r % ntx) * 32, k0 = (r / ntx) * 32;
    __shared__ float tile[32][33];
    const int tx = threadIdx.x & 31, ty = threadIdx.x >> 5;
    #pragma unroll
    for (int i = ty; i < 32; i += 8)
        tile[i][tx] = in[(size_t)(k0 + i) * N + n0 + tx];
    __syncthreads();
    #pragma unroll
    for (int i = ty; i < 32; i += 8)
        o[(size_t)(n0 + i) * K + k0 + tx] = (__bf16)tile[tx][i];
}

// C[M][N] = A[M][K] * Bt[N][K]^T ; EPI 0: fp32 out, 1: relu->bf16 out
template<int EPI>
__global__ __launch_bounds__(256)
void gemm_bt(const __bf16* __restrict__ A, const __bf16* __restrict__ Bt,
             void* __restrict__ Cv, int M, int N, int K) {
    __shared__ __bf16 As[128 * 32];
    __shared__ __bf16 Bs[128 * 32];
    const int t = threadIdx.x;
    const int w = t >> 6, l = t & 63;
    const int l15 = l & 15, q4 = l >> 4;
    const int wr = w >> 1, wc = w & 1;
    const int m0 = blockIdx.y * 128, n0 = blockIdx.x * 128;

    const int row = t >> 2;          // 0..63
    const int kc  = (t & 3) * 8;     // element offset in K-tile
    const __bf16* ag0 = A  + (size_t)(m0 + row) * K + kc;
    const __bf16* ag1 = A  + (size_t)(m0 + row + 64) * K + kc;
    const __bf16* bg0 = Bt + (size_t)(n0 + row) * K + kc;
    const __bf16* bg1 = Bt + (size_t)(n0 + row + 64) * K + kc;
    __bf16* asw = As + w * 512;      // wave-uniform LDS base
    __bf16* bsw = Bs + w * 512;

    const int aoff = (wr * 64 + l15) * 32 + q4 * 8;
    const int boff = (wc * 64 + l15) * 32 + q4 * 8;

    f32x4 acc[4][4];
    #pragma unroll
    for (int i = 0; i < 4; i++)
        #pragma unroll
        for (int j = 0; j < 4; j++) acc[i][j] = (f32x4){0.f, 0.f, 0.f, 0.f};

    for (int k0 = 0; k0 < K; k0 += 32) {
        async_copy16(ag0 + k0, asw);
        async_copy16(ag1 + k0, asw + 2048);
        async_copy16(bg0 + k0, bsw);
        async_copy16(bg1 + k0, bsw + 2048);
        __syncthreads();
        bf16x8 af[4], bfr[4];
        #pragma unroll
        for (int i = 0; i < 4; i++) af[i]  = *(const bf16x8*)(As + aoff + i * 512);
        #pragma unroll
        for (int j = 0; j < 4; j++) bfr[j] = *(const bf16x8*)(Bs + boff + j * 512);
        #pragma unroll
        for (int i = 0; i < 4; i++)
            #pragma unroll
            for (int j = 0; j < 4; j++)
                acc[i][j] = __builtin_amdgcn_mfma_f32_16x16x32_bf16(af[i], bfr[j], acc[i][j], 0, 0, 0);
        __syncthreads();
    }

    const int r0 = m0 + wr * 64 + q4 * 4;
    const int c0 = n0 + wc * 64 + l15;
    if (EPI == 0) {
        float* C = (float*)Cv;
        #pragma unroll
        for (int i = 0; i < 4; i++)
            #pragma unroll
            for (int j = 0; j < 4; j++)
                #pragma unroll
                for (int r = 0; r < 4; r++)
                    C[(size_t)(r0 + i * 16 + r) * N + c0 + j * 16] = acc[i][j][r];
    } else {
        __bf16* C = (__bf16*)Cv;
        #pragma unroll
        for (int i = 0; i < 4; i++)
            #pragma unroll
            for (int j = 0; j < 4; j++)
                #pragma unroll
                for (int r = 0; r < 4; r++)
                    C[(size_t)(r0 + i * 16 + r) * N + c0 + j * 16] = (__bf16)fmaxf(acc[i][j][r], 0.0f);
    }
}

__global__ void zero_f_kernel(float* p, int n) {
    const int i = blockIdx.x * 256 + threadIdx.x;
    if (i < n) p[i] = 0.0f;
}

// column sums of V (qkv cols 2048..3071) -> vmean (SUM over all 2048 rows)
__global__ __launch_bounds__(256)
void vmean_kernel(const float* __restrict__ qkv, float* __restrict__ vmean) {
    const int d = blockIdx.x * 256 + threadIdx.x;      // 0..1023
    const int s0 = blockIdx.y * 128;
    float s = 0.f;
    for (int i = 0; i < 128; i++) s += qkv[(size_t)(s0 + i) * 3072 + 2048 + d];
    atomicAdd(&vmean[d], s);
}

// ---------------- MFMA attention ----------------
// local rows: block = (32-row q-tile, head). Column set = window ∪ out-of-window
// globals (<=128 cols). Pad rows get vmean/2048. Global rows skipped here.
__global__ __launch_bounds__(256)
void attn_local(const float* __restrict__ qkv, const int* __restrict__ Tp,
                const int* __restrict__ isg, const int* __restrict__ gcols,
                const int* __restrict__ ngcp, const float* __restrict__ vmean,
                __bf16* __restrict__ ctx) {
    const int qt0 = blockIdx.x * 32, h = blockIdx.y, hd = h * 128;
    const int t = threadIdx.x;
    __shared__ __bf16 Qs[32 * 136];
    __shared__ __bf16 Ks[128 * 136];
    __shared__ __bf16 Vs[128 * 136];
    __shared__ __bf16 Ps[32 * 136];
    __shared__ float  Ss[32 * 129];
    __shared__ int cix[128], cgf[128], rtype[32];
    __shared__ int ncs;
    const int T = *Tp, ng = *ngcp;
    const int wl = max(qt0 - 32, 0), wh = min(qt0 + 63, S_LEN - 1);
    if (t == 0) ncs = 0;
    if (t < 32) { const int qr = qt0 + t; rtype[t] = isg[qr] ? 1 : (qr < T ? 0 : 2); }
    __syncthreads();
    if (t <= wh - wl) {
        const int c = wl + t, gf = isg[c];
        if (c < T || gf) { const int p = atomicAdd(&ncs, 1); cix[p] = c; cgf[p] = gf; }
    }
    if (t < ng) {
        const int c = gcols[t];
        if (c < wl || c > wh) { const int p = atomicAdd(&ncs, 1); cix[p] = c; cgf[p] = 1; }
    }
    // stage Q (independent of col list)
    {
        const int r = t >> 3, d0 = (t & 7) * 16;
        const float4* src = (const float4*)(qkv + (size_t)(qt0 + r) * 3072 + hd + d0);
        #pragma unroll
        for (int i = 0; i < 4; i++) {
            const float4 v = src[i];
            __bf16* q = &Qs[r * 136 + d0 + i * 4];
            q[0] = (__bf16)v.x; q[1] = (__bf16)v.y; q[2] = (__bf16)v.z; q[3] = (__bf16)v.w;
        }
    }
    __syncthreads();
    const int nc = ncs;
    if (nc + t < 128) { cix[nc + t] = -1; cgf[nc + t] = 0; }   // sentinels
    // stage K/V (j >= nc -> zero fill; don't read sentinel cix, it races)
    {
        const int j = t >> 1, d0 = (t & 1) * 64;
        const int ci = (j < nc) ? cix[j] : -1;
        if (ci >= 0) {
            const float4* kp = (const float4*)(qkv + (size_t)ci * 3072 + 1024 + hd + d0);
            const float4* vp = (const float4*)(qkv + (size_t)ci * 3072 + 2048 + hd + d0);
            #pragma unroll
            for (int i = 0; i < 16; i++) {
                const float4 kv = kp[i]; const float4 vv = vp[i];
                __bf16* kq = &Ks[j * 136 + d0 + i * 4];
                __bf16* vq = &Vs[j * 136 + d0 + i * 4];
                kq[0] = (__bf16)kv.x; kq[1] = (__bf16)kv.y; kq[2] = (__bf16)kv.z; kq[3] = (__bf16)kv.w;
                vq[0] = (__bf16)vv.x; vq[1] = (__bf16)vv.y; vq[2] = (__bf16)vv.z; vq[3] = (__bf16)vv.w;
            }
        } else {
            #pragma unroll
            for (int i = 0; i < 16; i++) {
                __bf16* kq = &Ks[j * 136 + d0 + i * 4];
                __bf16* vq = &Vs[j * 136 + d0 + i * 4];
                kq[0] = kq[1] = kq[2] = kq[3] = (__bf16)0.f;
                vq[0] = vq[1] = vq[2] = vq[3] = (__bf16)0.f;
            }
        }
    }
    __syncthreads();

    const int l = t & 63, w = t >> 6;
    const int l15 = l & 15, q4 = l >> 4;
    const int nb = w * 32;
    // S = Q K^T  (M=32, N=128, K=128)
    {
        f32x4 sacc[2][2];
        #pragma unroll
        for (int i = 0; i < 2; i++)
            #pragma unroll
            for (int j = 0; j < 2; j++) sacc[i][j] = (f32x4){0.f, 0.f, 0.f, 0.f};
        #pragma unroll
        for (int kk = 0; kk < 4; kk++) {
            const int k0 = kk * 32;
            bf16x8 af[2], bk[2];
            af[0] = *(const bf16x8*)&Qs[l15 * 136 + k0 + q4 * 8];
            af[1] = *(const bf16x8*)&Qs[(16 + l15) * 136 + k0 + q4 * 8];
            bk[0] = *(const bf16x8*)&Ks[(nb + l15) * 136 + k0 + q4 * 8];
            bk[1] = *(const bf16x8*)&Ks[(nb + 16 + l15) * 136 + k0 + q4 * 8];
            #pragma unroll
            for (int m2 = 0; m2 < 2; m2++)
                #pragma unroll
                for (int n2 = 0; n2 < 2; n2++)
                    sacc[m2][n2] = __builtin_amdgcn_mfma_f32_16x16x32_bf16(af[m2], bk[n2], sacc[m2][n2], 0, 0, 0);
        }
        #pragma unroll
        for (int m2 = 0; m2 < 2; m2++)
            #pragma unroll
            for (int n2 = 0; n2 < 2; n2++)
                #pragma unroll
                for (int r = 0; r < 4; r++) {
                    const int row = m2 * 16 + q4 * 4 + r;
                    const int col = nb + n2 * 16 + l15;
                    const int c = cix[col];
                    const int dd = qt0 + row - c;
                    const bool ok = (c >= 0) && (((unsigned)(dd + 32) <= 64u) || cgf[col]);
                    Ss[row * 129 + col] = ok ? sacc[m2][n2][r] * ATT_SCALE : -1e30f;
                }
    }
    __syncthreads();
    // softmax (normalized) -> Ps bf16
    {
        const int r = t >> 3, i = t & 7;
        float mx = -1e30f;
        for (int c = i; c < 128; c += 8) mx = fmaxf(mx, Ss[r * 129 + c]);
        #pragma unroll
        for (int off = 4; off > 0; off >>= 1) mx = fmaxf(mx, __shfl_down(mx, off, 8));
        mx = __shfl(mx, 0, 8);
        float sm = 0.f;
        for (int c = i; c < 128; c += 8) {
            const float s = Ss[r * 129 + c];
            const float p = (s > -1e29f) ? __expf(s - mx) : 0.f;
            Ss[r * 129 + c] = p;
            sm += p;
        }
        #pragma unroll
        for (int off = 4; off > 0; off >>= 1) sm += __shfl_down(sm, off, 8);
        sm = __shfl(sm, 0, 8);
        const float rl = 1.0f / fmaxf(sm, 1e-30f);
        for (int c = i; c < 128; c += 8) Ps[r * 136 + c] = (__bf16)(Ss[r * 129 + c] * rl);
    }
    __syncthreads();
    // O = P V  (M=32 rows, N=128 dims, K=128 cols)
    {
        f32x4 oacc[2][2];
        #pragma unroll
        for (int i = 0; i < 2; i++)
            #pragma unroll
            for (int j = 0; j < 2; j++) oacc[i][j] = (f32x4){0.f, 0.f, 0.f, 0.f};
        #pragma unroll
        for (int kk = 0; kk < 4; kk++) {
            const int k0 = kk * 32;
            bf16x8 ap[2], bv[2];
            ap[0] = *(const bf16x8*)&Ps[l15 * 136 + k0 + q4 * 8];
            ap[1] = *(const bf16x8*)&Ps[(16 + l15) * 136 + k0 + q4 * 8];
            #pragma unroll
            for (int n2 = 0; n2 < 2; n2++) {
                const int dimn = nb + n2 * 16 + l15;
                #pragma unroll
                for (int jj = 0; jj < 8; jj++)
                    bv[n2][jj] = Vs[(k0 + q4 * 8 + jj) * 136 + dimn];
            }
            #pragma unroll
            for (int m2 = 0; m2 < 2; m2++)
                #pragma unroll
                for (int n2 = 0; n2 < 2; n2++)
                    oacc[m2][n2] = __builtin_amdgcn_mfma_f32_16x16x32_bf16(ap[m2], bv[n2], oacc[m2][n2], 0, 0, 0);
        }
        #pragma unroll
        for (int m2 = 0; m2 < 2; m2++)
            #pragma unroll
            for (int n2 = 0; n2 < 2; n2++)
                #pragma unroll
                for (int r = 0; r < 4; r++) {
                    const int row = m2 * 16 + q4 * 4 + r;
                    const int dim = nb + n2 * 16 + l15;
                    const int rt = rtype[row];
                    const size_t o = (size_t)(qt0 + row) * D_MODEL + hd + dim;
                    if (rt == 0)      ctx[o] = (__bf16)oacc[m2][n2][r];
                    else if (rt == 2) ctx[o] = (__bf16)(vmean[hd + dim] * (1.0f / 2048.0f));
                }
    }
}

// global rows, partial flash over one 128-col chunk. block = (chunk, head).
__global__ __launch_bounds__(256)
void attn_gpart(const float* __restrict__ qkv, const int* __restrict__ Tp,
                const int* __restrict__ isg, const int* __restrict__ gcols,
                const int* __restrict__ ngcp, float* __restrict__ Og,
                float* __restrict__ mg, float* __restrict__ lg) {
    const int cb = blockIdx.x, h = blockIdx.y, hd = h * 128, c0 = cb * 128;
    const int t = threadIdx.x;
    const int ng = *ngcp, T = *Tp;
    if (ng == 0) return;
    __shared__ __bf16 Qs[32 * 136];
    __shared__ __bf16 Ks[128 * 136];
    __shared__ __bf16 Vs[128 * 136];
    __shared__ __bf16 Ps[32 * 136];
    __shared__ float  Ss[32 * 129];
    __shared__ int vf[128];
    // stage Q (gathered global rows)
    {
        const int r = t >> 3, d0 = (t & 7) * 16;
        if (r < ng) {
            const float4* src = (const float4*)(qkv + (size_t)gcols[r] * 3072 + hd + d0);
            #pragma unroll
            for (int i = 0; i < 4; i++) {
                const float4 v = src[i];
                __bf16* q = &Qs[r * 136 + d0 + i * 4];
                q[0] = (__bf16)v.x; q[1] = (__bf16)v.y; q[2] = (__bf16)v.z; q[3] = (__bf16)v.w;
            }
        } else {
            #pragma unroll
            for (int i = 0; i < 4; i++) {
                __bf16* q = &Qs[r * 136 + d0 + i * 4];
                q[0] = q[1] = q[2] = q[3] = (__bf16)0.f;
            }
        }
    }
    if (t < 128) { const int c = c0 + t; vf[t] = (c < T || isg[c]) ? 1 : 0; }
    // stage K/V chunk rows
    {
        const int j = t >> 1, d0 = (t & 1) * 64;
        const int ci = c0 + j;
        const float4* kp = (const float4*)(qkv + (size_t)ci * 3072 + 1024 + hd + d0);
        const float4* vp = (const float4*)(qkv + (size_t)ci * 3072 + 2048 + hd + d0);
        #pragma unroll
        for (int i = 0; i < 16; i++) {
            const float4 kv = kp[i]; const float4 vv = vp[i];
            __bf16* kq = &Ks[j * 136 + d0 + i * 4];
            __bf16* vq = &Vs[j * 136 + d0 + i * 4];
            kq[0] = (__bf16)kv.x; kq[1] = (__bf16)kv.y; kq[2] = (__bf16)kv.z; kq[3] = (__bf16)kv.w;
            vq[0] = (__bf16)vv.x; vq[1] = (__bf16)vv.y; vq[2] = (__bf16)vv.z; vq[3] = (__bf16)vv.w;
        }
    }
    __syncthreads();

    const int l = t & 63, w = t >> 6;
    const int l15 = l & 15, q4 = l >> 4;
    const int nb = w * 32;
    {
        f32x4 sacc[2][2];
        #pragma unroll
        for (int i = 0; i < 2; i++)
            #pragma unroll
            for (int j = 0; j < 2; j++) sacc[i][j] = (f32x4){0.f, 0.f, 0.f, 0.f};
        #pragma unroll
        for (int kk = 0; kk < 4; kk++) {
            const int k0 = kk * 32;
            bf16x8 af[2], bk[2];
            af[0] = *(const bf16x8*)&Qs[l15 * 136 + k0 + q4 * 8];
            af[1] = *(const bf16x8*)&Qs[(16 + l15) * 136 + k0 + q4 * 8];
            bk[0] = *(const bf16x8*)&Ks[(nb + l15) * 136 + k0 + q4 * 8];
            bk[1] = *(const bf16x8*)&Ks[(nb + 16 + l15) * 136 + k0 + q4 * 8];
            #pragma unroll
            for (int m2 = 0; m2 < 2; m2++)
                #pragma unroll
                for (int n2 = 0; n2 < 2; n2++)
                    sacc[m2][n2] = __builtin_amdgcn_mfma_f32_16x16x32_bf16(af[m2], bk[n2], sacc[m2][n2], 0, 0, 0);
        }
        #pragma unroll
        for (int m2 = 0; m2 < 2; m2++)
            #pragma unroll
            for (int n2 = 0; n2 < 2; n2++)
                #pragma unroll
                for (int r = 0; r < 4; r++) {
                    const int row = m2 * 16 + q4 * 4 + r;
                    const int col = nb + n2 * 16 + l15;
                    Ss[row * 129 + col] = vf[col] ? sacc[m2][n2][r] * ATT_SCALE : -1e30f;
                }
    }
    __syncthreads();
    // partial softmax: p = exp(s - m_c) (UNnormalized); save m_c, l_c
    {
        const int r = t >> 3, i = t & 7;
        float mx = -1e30f;
        for (int c = i; c < 128; c += 8) mx = fmaxf(mx, Ss[r * 129 + c]);
        #pragma unroll
        for (int off = 4; off > 0; off >>= 1) mx = fmaxf(mx, __shfl_down(mx, off, 8));
        mx = __shfl(mx, 0, 8);
        float sm = 0.f;
        for (int c = i; c < 128; c += 8) {
            const float s = Ss[r * 129 + c];
            const float p = (s > -1e29f) ? __expf(s - mx) : 0.f;
            Ps[r * 136 + c] = (__bf16)p;
            sm += p;
        }
        #pragma unroll
        for (int off = 4; off > 0; off >>= 1) sm += __shfl_down(sm, off, 8);
        if (i == 0) { mg[(h * 16 + cb) * 32 + r] = mx; lg[(h * 16 + cb) * 32 + r] = sm; }
    }
    __syncthreads();
    // O_c = P V
    {
        f32x4 oacc[2][2];
        #pragma unroll
        for (int i = 0; i < 2; i++)
            #pragma unroll
            for (int j = 0; j < 2; j++) oacc[i][j] = (f32x4){0.f, 0.f, 0.f, 0.f};
        #pragma unroll
        for (int kk = 0; kk < 4; kk++) {
            const int k0 = kk * 32;
            bf16x8 ap[2], bv[2];
            ap[0] = *(const bf16x8*)&Ps[l15 * 136 + k0 + q4 * 8];
            ap[1] = *(const bf16x8*)&Ps[(16 + l15) * 136 + k0 + q4 * 8];
            #pragma unroll
            for (int n2 = 0; n2 < 2; n2++) {
                const int dimn = nb + n2 * 16 + l15;
                #pragma unroll
                for (int jj = 0; jj < 8; jj++)
                    bv[n2][jj] = Vs[(k0 + q4 * 8 + jj) * 136 + dimn];
            }
            #pragma unroll
            for (int m2 = 0; m2 < 2; m2++)
                #pragma unroll
                for (int n2 = 0; n2 < 2; n2++)
                    oacc[m2][n2] = __builtin_amdgcn_mfma_f32_16x16x32_bf16(ap[m2], bv[n2], oacc[m2][n2], 0, 0, 0);
        }
        #pragma unroll
        for (int m2 = 0; m2 < 2; m2++)
            #pragma unroll
            for (int n2 = 0; n2 < 2; n2++)
                #pragma unroll
                for (int r = 0; r < 4; r++) {
                    const int row = m2 * 16 + q4 * 4 + r;
                    const int dim = nb + n2 * 16 + l15;
                    Og[((size_t)(h * 16 + cb) * 32 + row) * 128 + dim] = oacc[m2][n2][r];
                }
    }
}

// combine the 16 chunks for global rows
__global__ __launch_bounds__(256)
void attn_gcomb(const int* __restrict__ gcols, const int* __restrict__ ngcp,
                const float* __restrict__ Og, const float* __restrict__ mg,
                const float* __restrict__ lg, __bf16* __restrict__ ctx) {
    const int h = blockIdx.x, hd = h * 128, t = threadIdx.x;
    const int ng = *ngcp;
    const int r = t >> 3, i = t & 7;
    if (r >= ng) return;
    float M = -1e30f;
    #pragma unroll
    for (int cb = 0; cb < 16; cb++) M = fmaxf(M, mg[(h * 16 + cb) * 32 + r]);
    float e[16], L = 0.f;
    #pragma unroll
    for (int cb = 0; cb < 16; cb++) {
        e[cb] = __expf(mg[(h * 16 + cb) * 32 + r] - M);
        L += e[cb] * lg[(h * 16 + cb) * 32 + r];
    }
    const float rL = 1.0f / fmaxf(L, 1e-30f);
    const int grow = gcols[r];
    for (int d = i; d < 128; d += 8) {
        float o = 0.f;
        #pragma unroll
        for (int cb = 0; cb < 16; cb++)
            o += e[cb] * Og[((size_t)(h * 16 + cb) * 32 + r) * 128 + d];
        ctx[(size_t)grow * D_MODEL + hd + d] = (__bf16)(o * rL);
    }
}

// x = LN(y + r); writes fp32 (xo) + bf16 (xb)
__global__ __launch_bounds__(256)
void ln_kernel(const float* __restrict__ y, const float* __restrict__ r,
               const float* __restrict__ g, const float* __restrict__ b,
               float* __restrict__ xo, __bf16* __restrict__ xb) {
    const int row = blockIdx.x, t = threadIdx.x;
    const float* yr = y + (size_t)row * D_MODEL;
    const float* rr = r + (size_t)row * D_MODEL;
    __shared__ float red[4];
    float v[4]; float s = 0.f;
    #pragma unroll
    for (int i = 0; i < 4; i++) { const int d = t + i * 256; v[i] = yr[d] + rr[d]; s += v[i]; }
    s = blockRedSum<4>(s, red);
    const float mu = s * (1.0f / 1024.0f);
    float vs = 0.f;
    #pragma unroll
    for (int i = 0; i < 4; i++) { const float dd = v[i] - mu; vs += dd * dd; }
    vs = blockRedSum<4>(vs, red);
    const float rstd = rsqrtf(vs * (1.0f / 1024.0f) + 1e-5f);
    #pragma unroll
    for (int i = 0; i < 4; i++) {
        const int d = t + i * 256;
        const float o = g[d] * (v[i] - mu) * rstd + b[d];
        xo[(size_t)row * D_MODEL + d] = o;
        xb[(size_t)row * D_MODEL + d] = (__bf16)o;
    }
}

extern "C" void kernel_launch(void* const* d_in, const int* in_sizes, int n_in,
                              void* d_out, int out_size, void* d_ws, size_t ws_size,
                              hipStream_t stream) {
    const int*   Tp   = (const int*)  d_in[0];
    const float* enc  = (const float*)d_in[1];
    const int*   gidx = (const int*)  d_in[2];
    const float* Wq   = (const float*)d_in[3];
    const float* Wk   = (const float*)d_in[4];
    const float* Wv   = (const float*)d_in[5];
    const float* Wo   = (const float*)d_in[6];
    const float* ln1g = (const float*)d_in[7];
    const float* ln1b = (const float*)d_in[8];
    const float* W1   = (const float*)d_in[9];
    const float* W2   = (const float*)d_in[10];
    const float* ln2g = (const float*)d_in[11];
    const float* ln2b = (const float*)d_in[12];

    char* p = (char*)d_ws;
    size_t off = 0;
    auto alloc = [&](size_t bytes) -> void* {
        void* q = p + off;
        off += (bytes + 255) & ~(size_t)255;
        return q;
    };
    float*  x     = (float*) alloc((size_t)S_LEN * D_MODEL * 4);
    __bf16* xb    = (__bf16*)alloc((size_t)S_LEN * D_MODEL * 2);
    float*  qkv   = (float*) alloc((size_t)S_LEN * 3072 * 4);
    __bf16* ctx   = (__bf16*)alloc((size_t)S_LEN * D_MODEL * 2);
    float*  g1    = (float*) alloc((size_t)S_LEN * D_MODEL * 4);
    __bf16* h1    = (__bf16*)alloc((size_t)S_LEN * D_FF * 2);
    __bf16* wT    = (__bf16*)alloc((size_t)8 * 1024 * 1024 * 2);   // 6-matrix arena
    float*  vmean = (float*) alloc(1024 * 4);
    int*    isg   = (int*)   alloc(S_LEN * 4);
    int*    gcols = (int*)   alloc(S_LEN * 4);
    int*    ngc   = (int*)   alloc(256);
    float*  Og    = (float*) alloc((size_t)8 * 16 * 32 * 128 * 4);
    float*  mgb   = (float*) alloc(8 * 16 * 32 * 4);
    float*  lgb   = (float*) alloc(8 * 16 * 32 * 4);

    init_x_kernel<<<S_LEN, 256, 0, stream>>>(enc, x, xb);
    mask_setup_kernel<<<1, 1024, 0, stream>>>(gidx, isg, gcols, ngc);

    for (int l = 0; l < NLAYER; l++) {
        const size_t lw = (size_t)l * 1024 * 1024;
        const size_t lf = (size_t)l * 1024 * 2048;
        // --- all 6 weight transposes in one dispatch ---
        transpose_all_kernel<<<8192, 256, 0, stream>>>(Wq + lw, Wk + lw, Wv + lw, Wo + lw,
                                                       W1 + lf, W2 + lf, wT);
        // --- QKV projection (fused N=3072) ---
        gemm_bt<0><<<dim3(24, 16), 256, 0, stream>>>(xb, wT, (void*)qkv, S_LEN, 3072, 1024);

        // --- attention (MFMA, local/global/pad split) ---
        zero_f_kernel<<<4, 256, 0, stream>>>(vmean, 1024);
        vmean_kernel<<<dim3(4, 16), 256, 0, stream>>>(qkv, vmean);
        attn_local<<<dim3(64, 8), 256, 0, stream>>>(qkv, Tp, isg, gcols, ngc, vmean, ctx);
        attn_gpart<<<dim3(16, 8), 256, 0, stream>>>(qkv, Tp, isg, gcols, ngc, Og, mgb, lgb);
        attn_gcomb<<<8, 256, 0, stream>>>(gcols, ngc, Og, mgb, lgb, ctx);

        // --- output projection + LN1 ---
        gemm_bt<0><<<dim3(8, 16), 256, 0, stream>>>(ctx, wT + (size_t)3 * 1024 * 1024, (void*)g1, S_LEN, 1024, 1024);
        ln_kernel<<<S_LEN, 256, 0, stream>>>(g1, x, ln1g + l * 1024, ln1b + l * 1024, x, xb);

        // --- FFN ---
        gemm_bt<1><<<dim3(16, 16), 256, 0, stream>>>(xb, wT + (size_t)4 * 1024 * 1024, (void*)h1, S_LEN, 2048, 1024);   // relu -> bf16
        gemm_bt<0><<<dim3(8, 16), 256, 0, stream>>>(h1, wT + (size_t)6 * 1024 * 1024, (void*)g1, S_LEN, 1024, 2048);
        float* xout = (l == NLAYER - 1) ? (float*)d_out : x;
        ln_kernel<<<S_LEN, 256, 0, stream>>>(g1, x, ln2g + l * 1024, ln2b + l * 1024, xout, xb);
    }
}

// Round 4
// 833.349 us; speedup vs baseline: 2.9581x; 1.2177x over previous
//
#include <hip/hip_runtime.h>
#include <cstdint>
#include <cstddef>

#define S_LEN  2048
#define D_MODEL 1024
#define D_FF   2048
#define NLAYER 4
// H=8, DK=128, WINDOW=64 (half=32)

typedef float  f32x4  __attribute__((ext_vector_type(4)));
typedef __bf16 bf16x8 __attribute__((ext_vector_type(8)));

#define ATT_SCALE 0.08838834764831845f   // 1/sqrt(128)

__device__ __forceinline__ void async_copy16(const void* g, void* s) {
    __builtin_amdgcn_global_load_lds((const __attribute__((address_space(1))) void*)g,
                                     (__attribute__((address_space(3))) void*)s, 16, 0, 0);
}

template<int NW>
__device__ __forceinline__ float blockRedSum(float v, float* red) {
    #pragma unroll
    for (int off = 32; off > 0; off >>= 1) v += __shfl_down(v, off);
    const int t = threadIdx.x;
    if ((t & 63) == 0) red[t >> 6] = v;
    __syncthreads();
    float r = red[0];
    #pragma unroll
    for (int i = 1; i < NW; i++) r += red[i];
    __syncthreads();
    return r;
}

// x = 2*enc + sinusoidal_pe; writes fp32 + bf16
__global__ __launch_bounds__(256)
void init_x_kernel(const float* __restrict__ enc, float* __restrict__ x, __bf16* __restrict__ xb) {
    const int s = blockIdx.x, t = threadIdx.x;
    #pragma unroll
    for (int i = 0; i < 4; i++) {
        const int d = t + i * 256;
        const float freq = expf(-(float)(d & ~1) * (9.210340371976184f / 1024.0f));
        const float ang = (float)s * freq;
        const float pe = (d & 1) ? cosf(ang) : sinf(ang);
        const float v = 2.0f * enc[(size_t)s * D_MODEL + d] + pe;
        x[(size_t)s * D_MODEL + d] = v;
        xb[(size_t)s * D_MODEL + d] = (__bf16)v;
    }
}

// is_global flags + compacted (unordered, deduped) global column list — all in LDS
__global__ __launch_bounds__(1024)
void mask_setup_kernel(const int* __restrict__ gidx, int* __restrict__ isg,
                       int* __restrict__ gcols, int* __restrict__ ngc) {
    __shared__ int gsh[32];
    __shared__ int cnt;
    const int t = threadIdx.x;
    if (t < 32) {
        const int g = gidx[t] / 15;      // gidx >= 0
        gsh[t] = (g >= 0 && g < S_LEN) ? g : -1;
    }
    if (t == 0) cnt = 0;
    __syncthreads();
    #pragma unroll
    for (int i = 0; i < 2; i++) {
        const int s = t + i * 1024;
        int f = 0;
        #pragma unroll
        for (int j = 0; j < 32; j++) f |= (gsh[j] == s) ? 1 : 0;
        isg[s] = f;
        if (f) { const int p = atomicAdd(&cnt, 1); gcols[p] = s; }
    }
    __syncthreads();
    if (t == 0) *ngc = cnt;
}

// All 6 weight transposes of one layer in a single dispatch.
// fp32 [K][N] -> bf16 [N][K]. Arena layout (elements):
//   WqT 0..1M, WkT 1M..2M, WvT 2M..3M, WoT 3M..4M, W1T 4M..6M, W2T 6M..8M
__global__ __launch_bounds__(256)
void transpose_all_kernel(const float* __restrict__ Wq, const float* __restrict__ Wk,
                          const float* __restrict__ Wv, const float* __restrict__ Wo,
                          const float* __restrict__ W1, const float* __restrict__ W2,
                          __bf16* __restrict__ out) {
    int bid = blockIdx.x;
    const float* in; __bf16* o; int K, N, r;
    if (bid < 4096) {
        const int m = bid >> 10; r = bid & 1023; K = 1024; N = 1024;
        in = (m == 0) ? Wq : (m == 1) ? Wk : (m == 2) ? Wv : Wo;
        o  = out + (size_t)m * 1024 * 1024;
    } else {
        bid -= 4096;
        const int m = bid >> 11; r = bid & 2047;
        if (m == 0) { in = W1; K = 1024; N = 2048; o = out + (size_t)4 * 1024 * 1024; }
        else        { in = W2; K = 2048; N = 1024; o = out + (size_t)6 * 1024 * 1024; }
    }
    const int ntx = N >> 5;
    const int n0 = (r % ntx) * 32, k0 = (r / ntx) * 32;
    __shared__ float tile[32][33];
    const int tx = threadIdx.x & 31, ty = threadIdx.x >> 5;
    #pragma unroll
    for (int i = ty; i < 32; i += 8)
        tile[i][tx] = in[(size_t)(k0 + i) * N + n0 + tx];
    __syncthreads();
    #pragma unroll
    for (int i = ty; i < 32; i += 8)
        o[(size_t)(n0 + i) * K + k0 + tx] = (__bf16)tile[tx][i];
}

// C[M][N] = A[M][K] * Bt[N][K]^T. Tile BM x BN (64 or 128), BK=32, 256 thr, 4 waves 2x2.
// EPI 0: fp32 out, 1: relu->bf16, 2: bf16
// Small tiles give 2-8 co-resident blocks/CU -> inter-block latency hiding
// (these shapes are latency-bound: the 2-barrier K-loop drains vmcnt(0) each iter).
template<int BM, int BN, int EPI>
__global__ __launch_bounds__(256)
void gemm_bt(const __bf16* __restrict__ A, const __bf16* __restrict__ Bt,
             void* __restrict__ Cv, int M, int N, int K) {
    constexpr int WM = BM / 2, WN = BN / 2;
    constexpr int MI = WM / 16, NI = WN / 16;
    __shared__ __bf16 As[BM * 32];
    __shared__ __bf16 Bs[BN * 32];
    const int t = threadIdx.x;
    const int w = t >> 6, l = t & 63;
    const int l15 = l & 15, q4 = l >> 4;
    const int wr = w >> 1, wc = w & 1;
    const int m0 = blockIdx.y * BM, n0 = blockIdx.x * BN;

    const int row = t >> 2;          // 0..63
    const int kc  = (t & 3) * 8;     // element offset in K-tile
    const __bf16* ag0 = A  + (size_t)(m0 + row) * K + kc;
    const __bf16* bg0 = Bt + (size_t)(n0 + row) * K + kc;
    __bf16* asw = As + w * 512;      // wave-uniform LDS base
    __bf16* bsw = Bs + w * 512;

    const int aoff = (wr * WM + l15) * 32 + q4 * 8;
    const int boff = (wc * WN + l15) * 32 + q4 * 8;

    f32x4 acc[MI][NI];
    #pragma unroll
    for (int i = 0; i < MI; i++)
        #pragma unroll
        for (int j = 0; j < NI; j++) acc[i][j] = (f32x4){0.f, 0.f, 0.f, 0.f};

    for (int k0 = 0; k0 < K; k0 += 32) {
        async_copy16(ag0 + k0, asw);
        if constexpr (BM == 128) async_copy16(ag0 + (size_t)64 * K + k0, asw + 2048);
        async_copy16(bg0 + k0, bsw);
        if constexpr (BN == 128) async_copy16(bg0 + (size_t)64 * K + k0, bsw + 2048);
        __syncthreads();
        bf16x8 af[MI], bfr[NI];
        #pragma unroll
        for (int i = 0; i < MI; i++) af[i]  = *(const bf16x8*)(As + aoff + i * 512);
        #pragma unroll
        for (int j = 0; j < NI; j++) bfr[j] = *(const bf16x8*)(Bs + boff + j * 512);
        #pragma unroll
        for (int i = 0; i < MI; i++)
            #pragma unroll
            for (int j = 0; j < NI; j++)
                acc[i][j] = __builtin_amdgcn_mfma_f32_16x16x32_bf16(af[i], bfr[j], acc[i][j], 0, 0, 0);
        __syncthreads();
    }

    const int r0 = m0 + wr * WM + q4 * 4;
    const int c0 = n0 + wc * WN + l15;
    if constexpr (EPI == 0) {
        float* C = (float*)Cv;
        #pragma unroll
        for (int i = 0; i < MI; i++)
            #pragma unroll
            for (int j = 0; j < NI; j++)
                #pragma unroll
                for (int r = 0; r < 4; r++)
                    C[(size_t)(r0 + i * 16 + r) * N + c0 + j * 16] = acc[i][j][r];
    } else if constexpr (EPI == 1) {
        __bf16* C = (__bf16*)Cv;
        #pragma unroll
        for (int i = 0; i < MI; i++)
            #pragma unroll
            for (int j = 0; j < NI; j++)
                #pragma unroll
                for (int r = 0; r < 4; r++)
                    C[(size_t)(r0 + i * 16 + r) * N + c0 + j * 16] = (__bf16)fmaxf(acc[i][j][r], 0.0f);
    } else {
        __bf16* C = (__bf16*)Cv;
        #pragma unroll
        for (int i = 0; i < MI; i++)
            #pragma unroll
            for (int j = 0; j < NI; j++)
                #pragma unroll
                for (int r = 0; r < 4; r++)
                    C[(size_t)(r0 + i * 16 + r) * N + c0 + j * 16] = (__bf16)acc[i][j][r];
    }
}

__global__ void zero_f_kernel(float* p, int n) {
    const int i = blockIdx.x * 256 + threadIdx.x;
    if (i < n) p[i] = 0.0f;
}

// column sums of V (qkvb cols 2048..3071, bf16) -> vmean (SUM over all 2048 rows)
__global__ __launch_bounds__(256)
void vmean_kernel(const __bf16* __restrict__ qkvb, float* __restrict__ vmean) {
    const int d = blockIdx.x * 256 + threadIdx.x;      // 0..1023
    const int s0 = blockIdx.y * 128;
    float s = 0.f;
    for (int i = 0; i < 128; i++) s += (float)qkvb[(size_t)(s0 + i) * 3072 + 2048 + d];
    atomicAdd(&vmean[d], s);
}

// ---------------- MFMA attention (bf16 qkv input) ----------------
__global__ __launch_bounds__(256)
void attn_local(const __bf16* __restrict__ qkvb, const int* __restrict__ Tp,
                const int* __restrict__ isg, const int* __restrict__ gcols,
                const int* __restrict__ ngcp, const float* __restrict__ vmean,
                __bf16* __restrict__ ctx) {
    const int qt0 = blockIdx.x * 32, h = blockIdx.y, hd = h * 128;
    const int t = threadIdx.x;
    __shared__ __bf16 Qs[32 * 136];
    __shared__ __bf16 Ks[128 * 136];
    __shared__ __bf16 Vs[128 * 136];
    __shared__ __bf16 Ps[32 * 136];
    __shared__ float  Ss[32 * 129];
    __shared__ int cix[128], cgf[128], rtype[32];
    __shared__ int ncs;
    const int T = *Tp, ng = *ngcp;
    const int wl = max(qt0 - 32, 0), wh = min(qt0 + 63, S_LEN - 1);
    if (t == 0) ncs = 0;
    if (t < 32) { const int qr = qt0 + t; rtype[t] = isg[qr] ? 1 : (qr < T ? 0 : 2); }
    __syncthreads();
    if (t <= wh - wl) {
        const int c = wl + t, gf = isg[c];
        if (c < T || gf) { const int p = atomicAdd(&ncs, 1); cix[p] = c; cgf[p] = gf; }
    }
    if (t < ng) {
        const int c = gcols[t];
        if (c < wl || c > wh) { const int p = atomicAdd(&ncs, 1); cix[p] = c; cgf[p] = 1; }
    }
    // stage Q
    {
        const int r = t >> 3, d0 = (t & 7) * 16;
        const bf16x8* src = (const bf16x8*)(qkvb + (size_t)(qt0 + r) * 3072 + hd + d0);
        *(bf16x8*)&Qs[r * 136 + d0]     = src[0];
        *(bf16x8*)&Qs[r * 136 + d0 + 8] = src[1];
    }
    __syncthreads();
    const int nc = ncs;
    if (nc + t < 128) { cix[nc + t] = -1; cgf[nc + t] = 0; }   // sentinels
    // stage K/V
    {
        const int j = t >> 1, d0 = (t & 1) * 64;
        const int ci = (j < nc) ? cix[j] : -1;
        if (ci >= 0) {
            const bf16x8* kp = (const bf16x8*)(qkvb + (size_t)ci * 3072 + 1024 + hd + d0);
            const bf16x8* vp = (const bf16x8*)(qkvb + (size_t)ci * 3072 + 2048 + hd + d0);
            #pragma unroll
            for (int i = 0; i < 8; i++) {
                *(bf16x8*)&Ks[j * 136 + d0 + i * 8] = kp[i];
                *(bf16x8*)&Vs[j * 136 + d0 + i * 8] = vp[i];
            }
        } else {
            #pragma unroll
            for (int i = 0; i < 8; i++) {
                *(bf16x8*)&Ks[j * 136 + d0 + i * 8] = (bf16x8)(__bf16)0.f;
                *(bf16x8*)&Vs[j * 136 + d0 + i * 8] = (bf16x8)(__bf16)0.f;
            }
        }
    }
    __syncthreads();

    const int l = t & 63, w = t >> 6;
    const int l15 = l & 15, q4 = l >> 4;
    const int nb = w * 32;
    // S = Q K^T
    {
        f32x4 sacc[2][2];
        #pragma unroll
        for (int i = 0; i < 2; i++)
            #pragma unroll
            for (int j = 0; j < 2; j++) sacc[i][j] = (f32x4){0.f, 0.f, 0.f, 0.f};
        #pragma unroll
        for (int kk = 0; kk < 4; kk++) {
            const int k0 = kk * 32;
            bf16x8 af[2], bk[2];
            af[0] = *(const bf16x8*)&Qs[l15 * 136 + k0 + q4 * 8];
            af[1] = *(const bf16x8*)&Qs[(16 + l15) * 136 + k0 + q4 * 8];
            bk[0] = *(const bf16x8*)&Ks[(nb + l15) * 136 + k0 + q4 * 8];
            bk[1] = *(const bf16x8*)&Ks[(nb + 16 + l15) * 136 + k0 + q4 * 8];
            #pragma unroll
            for (int m2 = 0; m2 < 2; m2++)
                #pragma unroll
                for (int n2 = 0; n2 < 2; n2++)
                    sacc[m2][n2] = __builtin_amdgcn_mfma_f32_16x16x32_bf16(af[m2], bk[n2], sacc[m2][n2], 0, 0, 0);
        }
        #pragma unroll
        for (int m2 = 0; m2 < 2; m2++)
            #pragma unroll
            for (int n2 = 0; n2 < 2; n2++)
                #pragma unroll
                for (int r = 0; r < 4; r++) {
                    const int row = m2 * 16 + q4 * 4 + r;
                    const int col = nb + n2 * 16 + l15;
                    const int c = cix[col];
                    const int dd = qt0 + row - c;
                    const bool ok = (c >= 0) && (((unsigned)(dd + 32) <= 64u) || cgf[col]);
                    Ss[row * 129 + col] = ok ? sacc[m2][n2][r] * ATT_SCALE : -1e30f;
                }
    }
    __syncthreads();
    // softmax (normalized) -> Ps bf16
    {
        const int r = t >> 3, i = t & 7;
        float mx = -1e30f;
        for (int c = i; c < 128; c += 8) mx = fmaxf(mx, Ss[r * 129 + c]);
        #pragma unroll
        for (int off = 4; off > 0; off >>= 1) mx = fmaxf(mx, __shfl_down(mx, off, 8));
        mx = __shfl(mx, 0, 8);
        float sm = 0.f;
        for (int c = i; c < 128; c += 8) {
            const float s = Ss[r * 129 + c];
            const float p = (s > -1e29f) ? __expf(s - mx) : 0.f;
            Ss[r * 129 + c] = p;
            sm += p;
        }
        #pragma unroll
        for (int off = 4; off > 0; off >>= 1) sm += __shfl_down(sm, off, 8);
        sm = __shfl(sm, 0, 8);
        const float rl = 1.0f / fmaxf(sm, 1e-30f);
        for (int c = i; c < 128; c += 8) Ps[r * 136 + c] = (__bf16)(Ss[r * 129 + c] * rl);
    }
    __syncthreads();
    // O = P V
    {
        f32x4 oacc[2][2];
        #pragma unroll
        for (int i = 0; i < 2; i++)
            #pragma unroll
            for (int j = 0; j < 2; j++) oacc[i][j] = (f32x4){0.f, 0.f, 0.f, 0.f};
        #pragma unroll
        for (int kk = 0; kk < 4; kk++) {
            const int k0 = kk * 32;
            bf16x8 ap[2], bv[2];
            ap[0] = *(const bf16x8*)&Ps[l15 * 136 + k0 + q4 * 8];
            ap[1] = *(const bf16x8*)&Ps[(16 + l15) * 136 + k0 + q4 * 8];
            #pragma unroll
            for (int n2 = 0; n2 < 2; n2++) {
                const int dimn = nb + n2 * 16 + l15;
                #pragma unroll
                for (int jj = 0; jj < 8; jj++)
                    bv[n2][jj] = Vs[(k0 + q4 * 8 + jj) * 136 + dimn];
            }
            #pragma unroll
            for (int m2 = 0; m2 < 2; m2++)
                #pragma unroll
                for (int n2 = 0; n2 < 2; n2++)
                    oacc[m2][n2] = __builtin_amdgcn_mfma_f32_16x16x32_bf16(ap[m2], bv[n2], oacc[m2][n2], 0, 0, 0);
        }
        #pragma unroll
        for (int m2 = 0; m2 < 2; m2++)
            #pragma unroll
            for (int n2 = 0; n2 < 2; n2++)
                #pragma unroll
                for (int r = 0; r < 4; r++) {
                    const int row = m2 * 16 + q4 * 4 + r;
                    const int dim = nb + n2 * 16 + l15;
                    const int rt = rtype[row];
                    const size_t o = (size_t)(qt0 + row) * D_MODEL + hd + dim;
                    if (rt == 0)      ctx[o] = (__bf16)oacc[m2][n2][r];
                    else if (rt == 2) ctx[o] = (__bf16)(vmean[hd + dim] * (1.0f / 2048.0f));
                }
    }
}

// global rows, partial flash over one 128-col chunk. block = (chunk, head).
__global__ __launch_bounds__(256)
void attn_gpart(const __bf16* __restrict__ qkvb, const int* __restrict__ Tp,
                const int* __restrict__ isg, const int* __restrict__ gcols,
                const int* __restrict__ ngcp, float* __restrict__ Og,
                float* __restrict__ mg, float* __restrict__ lg) {
    const int cb = blockIdx.x, h = blockIdx.y, hd = h * 128, c0 = cb * 128;
    const int t = threadIdx.x;
    const int ng = *ngcp, T = *Tp;
    if (ng == 0) return;
    __shared__ __bf16 Qs[32 * 136];
    __shared__ __bf16 Ks[128 * 136];
    __shared__ __bf16 Vs[128 * 136];
    __shared__ __bf16 Ps[32 * 136];
    __shared__ float  Ss[32 * 129];
    __shared__ int vf[128];
    // stage Q (gathered global rows)
    {
        const int r = t >> 3, d0 = (t & 7) * 16;
        if (r < ng) {
            const bf16x8* src = (const bf16x8*)(qkvb + (size_t)gcols[r] * 3072 + hd + d0);
            *(bf16x8*)&Qs[r * 136 + d0]     = src[0];
            *(bf16x8*)&Qs[r * 136 + d0 + 8] = src[1];
        } else {
            *(bf16x8*)&Qs[r * 136 + d0]     = (bf16x8)(__bf16)0.f;
            *(bf16x8*)&Qs[r * 136 + d0 + 8] = (bf16x8)(__bf16)0.f;
        }
    }
    if (t < 128) { const int c = c0 + t; vf[t] = (c < T || isg[c]) ? 1 : 0; }
    // stage K/V chunk rows
    {
        const int j = t >> 1, d0 = (t & 1) * 64;
        const int ci = c0 + j;
        const bf16x8* kp = (const bf16x8*)(qkvb + (size_t)ci * 3072 + 1024 + hd + d0);
        const bf16x8* vp = (const bf16x8*)(qkvb + (size_t)ci * 3072 + 2048 + hd + d0);
        #pragma unroll
        for (int i = 0; i < 8; i++) {
            *(bf16x8*)&Ks[j * 136 + d0 + i * 8] = kp[i];
            *(bf16x8*)&Vs[j * 136 + d0 + i * 8] = vp[i];
        }
    }
    __syncthreads();

    const int l = t & 63, w = t >> 6;
    const int l15 = l & 15, q4 = l >> 4;
    const int nb = w * 32;
    {
        f32x4 sacc[2][2];
        #pragma unroll
        for (int i = 0; i < 2; i++)
            #pragma unroll
            for (int j = 0; j < 2; j++) sacc[i][j] = (f32x4){0.f, 0.f, 0.f, 0.f};
        #pragma unroll
        for (int kk = 0; kk < 4; kk++) {
            const int k0 = kk * 32;
            bf16x8 af[2], bk[2];
            af[0] = *(const bf16x8*)&Qs[l15 * 136 + k0 + q4 * 8];
            af[1] = *(const bf16x8*)&Qs[(16 + l15) * 136 + k0 + q4 * 8];
            bk[0] = *(const bf16x8*)&Ks[(nb + l15) * 136 + k0 + q4 * 8];
            bk[1] = *(const bf16x8*)&Ks[(nb + 16 + l15) * 136 + k0 + q4 * 8];
            #pragma unroll
            for (int m2 = 0; m2 < 2; m2++)
                #pragma unroll
                for (int n2 = 0; n2 < 2; n2++)
                    sacc[m2][n2] = __builtin_amdgcn_mfma_f32_16x16x32_bf16(af[m2], bk[n2], sacc[m2][n2], 0, 0, 0);
        }
        #pragma unroll
        for (int m2 = 0; m2 < 2; m2++)
            #pragma unroll
            for (int n2 = 0; n2 < 2; n2++)
                #pragma unroll
                for (int r = 0; r < 4; r++) {
                    const int row = m2 * 16 + q4 * 4 + r;
                    const int col = nb + n2 * 16 + l15;
                    Ss[row * 129 + col] = vf[col] ? sacc[m2][n2][r] * ATT_SCALE : -1e30f;
                }
    }
    __syncthreads();
    // partial softmax: p = exp(s - m_c) (UNnormalized); save m_c, l_c
    {
        const int r = t >> 3, i = t & 7;
        float mx = -1e30f;
        for (int c = i; c < 128; c += 8) mx = fmaxf(mx, Ss[r * 129 + c]);
        #pragma unroll
        for (int off = 4; off > 0; off >>= 1) mx = fmaxf(mx, __shfl_down(mx, off, 8));
        mx = __shfl(mx, 0, 8);
        float sm = 0.f;
        for (int c = i; c < 128; c += 8) {
            const float s = Ss[r * 129 + c];
            const float p = (s > -1e29f) ? __expf(s - mx) : 0.f;
            Ps[r * 136 + c] = (__bf16)p;
            sm += p;
        }
        #pragma unroll
        for (int off = 4; off > 0; off >>= 1) sm += __shfl_down(sm, off, 8);
        if (i == 0) { mg[(h * 16 + cb) * 32 + r] = mx; lg[(h * 16 + cb) * 32 + r] = sm; }
    }
    __syncthreads();
    // O_c = P V
    {
        f32x4 oacc[2][2];
        #pragma unroll
        for (int i = 0; i < 2; i++)
            #pragma unroll
            for (int j = 0; j < 2; j++) oacc[i][j] = (f32x4){0.f, 0.f, 0.f, 0.f};
        #pragma unroll
        for (int kk = 0; kk < 4; kk++) {
            const int k0 = kk * 32;
            bf16x8 ap[2], bv[2];
            ap[0] = *(const bf16x8*)&Ps[l15 * 136 + k0 + q4 * 8];
            ap[1] = *(const bf16x8*)&Ps[(16 + l15) * 136 + k0 + q4 * 8];
            #pragma unroll
            for (int n2 = 0; n2 < 2; n2++) {
                const int dimn = nb + n2 * 16 + l15;
                #pragma unroll
                for (int jj = 0; jj < 8; jj++)
                    bv[n2][jj] = Vs[(k0 + q4 * 8 + jj) * 136 + dimn];
            }
            #pragma unroll
            for (int m2 = 0; m2 < 2; m2++)
                #pragma unroll
                for (int n2 = 0; n2 < 2; n2++)
                    oacc[m2][n2] = __builtin_amdgcn_mfma_f32_16x16x32_bf16(ap[m2], bv[n2], oacc[m2][n2], 0, 0, 0);
        }
        #pragma unroll
        for (int m2 = 0; m2 < 2; m2++)
            #pragma unroll
            for (int n2 = 0; n2 < 2; n2++)
                #pragma unroll
                for (int r = 0; r < 4; r++) {
                    const int row = m2 * 16 + q4 * 4 + r;
                    const int dim = nb + n2 * 16 + l15;
                    Og[((size_t)(h * 16 + cb) * 32 + row) * 128 + dim] = oacc[m2][n2][r];
                }
    }
}

// combine the 16 chunks for global rows
__global__ __launch_bounds__(256)
void attn_gcomb(const int* __restrict__ gcols, const int* __restrict__ ngcp,
                const float* __restrict__ Og, const float* __restrict__ mg,
                const float* __restrict__ lg, __bf16* __restrict__ ctx) {
    const int h = blockIdx.x, hd = h * 128, t = threadIdx.x;
    const int ng = *ngcp;
    const int r = t >> 3, i = t & 7;
    if (r >= ng) return;
    float M = -1e30f;
    #pragma unroll
    for (int cb = 0; cb < 16; cb++) M = fmaxf(M, mg[(h * 16 + cb) * 32 + r]);
    float e[16], L = 0.f;
    #pragma unroll
    for (int cb = 0; cb < 16; cb++) {
        e[cb] = __expf(mg[(h * 16 + cb) * 32 + r] - M);
        L += e[cb] * lg[(h * 16 + cb) * 32 + r];
    }
    const float rL = 1.0f / fmaxf(L, 1e-30f);
    const int grow = gcols[r];
    for (int d = i; d < 128; d += 8) {
        float o = 0.f;
        #pragma unroll
        for (int cb = 0; cb < 16; cb++)
            o += e[cb] * Og[((size_t)(h * 16 + cb) * 32 + r) * 128 + d];
        ctx[(size_t)grow * D_MODEL + hd + d] = (__bf16)(o * rL);
    }
}

// x = LN(y + r); writes fp32 (xo) + bf16 (xb)
__global__ __launch_bounds__(256)
void ln_kernel(const float* __restrict__ y, const float* __restrict__ r,
               const float* __restrict__ g, const float* __restrict__ b,
               float* __restrict__ xo, __bf16* __restrict__ xb) {
    const int row = blockIdx.x, t = threadIdx.x;
    const float* yr = y + (size_t)row * D_MODEL;
    const float* rr = r + (size_t)row * D_MODEL;
    __shared__ float red[4];
    float v[4]; float s = 0.f;
    #pragma unroll
    for (int i = 0; i < 4; i++) { const int d = t + i * 256; v[i] = yr[d] + rr[d]; s += v[i]; }
    s = blockRedSum<4>(s, red);
    const float mu = s * (1.0f / 1024.0f);
    float vs = 0.f;
    #pragma unroll
    for (int i = 0; i < 4; i++) { const float dd = v[i] - mu; vs += dd * dd; }
    vs = blockRedSum<4>(vs, red);
    const float rstd = rsqrtf(vs * (1.0f / 1024.0f) + 1e-5f);
    #pragma unroll
    for (int i = 0; i < 4; i++) {
        const int d = t + i * 256;
        const float o = g[d] * (v[i] - mu) * rstd + b[d];
        xo[(size_t)row * D_MODEL + d] = o;
        xb[(size_t)row * D_MODEL + d] = (__bf16)o;
    }
}

extern "C" void kernel_launch(void* const* d_in, const int* in_sizes, int n_in,
                              void* d_out, int out_size, void* d_ws, size_t ws_size,
                              hipStream_t stream) {
    const int*   Tp   = (const int*)  d_in[0];
    const float* enc  = (const float*)d_in[1];
    const int*   gidx = (const int*)  d_in[2];
    const float* Wq   = (const float*)d_in[3];
    const float* Wk   = (const float*)d_in[4];
    const float* Wv   = (const float*)d_in[5];
    const float* Wo   = (const float*)d_in[6];
    const float* ln1g = (const float*)d_in[7];
    const float* ln1b = (const float*)d_in[8];
    const float* W1   = (const float*)d_in[9];
    const float* W2   = (const float*)d_in[10];
    const float* ln2g = (const float*)d_in[11];
    const float* ln2b = (const float*)d_in[12];

    char* p = (char*)d_ws;
    size_t off = 0;
    auto alloc = [&](size_t bytes) -> void* {
        void* q = p + off;
        off += (bytes + 255) & ~(size_t)255;
        return q;
    };
    float*  x     = (float*) alloc((size_t)S_LEN * D_MODEL * 4);
    __bf16* xb    = (__bf16*)alloc((size_t)S_LEN * D_MODEL * 2);
    __bf16* qkvb  = (__bf16*)alloc((size_t)S_LEN * 3072 * 2);
    __bf16* ctx   = (__bf16*)alloc((size_t)S_LEN * D_MODEL * 2);
    float*  g1    = (float*) alloc((size_t)S_LEN * D_MODEL * 4);
    __bf16* h1    = (__bf16*)alloc((size_t)S_LEN * D_FF * 2);
    __bf16* wT    = (__bf16*)alloc((size_t)8 * 1024 * 1024 * 2);   // 6-matrix arena
    float*  vmean = (float*) alloc(1024 * 4);
    int*    isg   = (int*)   alloc(S_LEN * 4);
    int*    gcols = (int*)   alloc(S_LEN * 4);
    int*    ngc   = (int*)   alloc(256);
    float*  Og    = (float*) alloc((size_t)8 * 16 * 32 * 128 * 4);
    float*  mgb   = (float*) alloc(8 * 16 * 32 * 4);
    float*  lgb   = (float*) alloc(8 * 16 * 32 * 4);

    init_x_kernel<<<S_LEN, 256, 0, stream>>>(enc, x, xb);
    mask_setup_kernel<<<1, 1024, 0, stream>>>(gidx, isg, gcols, ngc);

    for (int l = 0; l < NLAYER; l++) {
        const size_t lw = (size_t)l * 1024 * 1024;
        const size_t lf = (size_t)l * 1024 * 2048;
        transpose_all_kernel<<<8192, 256, 0, stream>>>(Wq + lw, Wk + lw, Wv + lw, Wo + lw,
                                                       W1 + lf, W2 + lf, wT);
        // --- QKV projection (fused N=3072, bf16 out), 64x128 tiles -> 768 blocks ---
        gemm_bt<64, 128, 2><<<dim3(24, 32), 256, 0, stream>>>(xb, wT, (void*)qkvb, S_LEN, 3072, 1024);

        // --- attention (MFMA, local/global/pad split) ---
        zero_f_kernel<<<4, 256, 0, stream>>>(vmean, 1024);
        vmean_kernel<<<dim3(4, 16), 256, 0, stream>>>(qkvb, vmean);
        attn_local<<<dim3(64, 8), 256, 0, stream>>>(qkvb, Tp, isg, gcols, ngc, vmean, ctx);
        attn_gpart<<<dim3(16, 8), 256, 0, stream>>>(qkvb, Tp, isg, gcols, ngc, Og, mgb, lgb);
        attn_gcomb<<<8, 256, 0, stream>>>(gcols, ngc, Og, mgb, lgb, ctx);

        // --- output projection + LN1 (64x64 tiles -> 512 blocks) ---
        gemm_bt<64, 64, 0><<<dim3(16, 32), 256, 0, stream>>>(ctx, wT + (size_t)3 * 1024 * 1024, (void*)g1, S_LEN, 1024, 1024);
        ln_kernel<<<S_LEN, 256, 0, stream>>>(g1, x, ln1g + l * 1024, ln1b + l * 1024, x, xb);

        // --- FFN (FFN1 64x64 -> 1024 blocks; FFN2 64x64 -> 512 blocks) ---
        gemm_bt<64, 64, 1><<<dim3(32, 32), 256, 0, stream>>>(xb, wT + (size_t)4 * 1024 * 1024, (void*)h1, S_LEN, 2048, 1024);
        gemm_bt<64, 64, 0><<<dim3(16, 32), 256, 0, stream>>>(h1, wT + (size_t)6 * 1024 * 1024, (void*)g1, S_LEN, 1024, 2048);
        float* xout = (l == NLAYER - 1) ? (float*)d_out : x;
        ln_kernel<<<S_LEN, 256, 0, stream>>>(g1, x, ln2g + l * 1024, ln2b + l * 1024, xout, xb);
    }
}

// Round 5
// 768.580 us; speedup vs baseline: 3.2073x; 1.0843x over previous
//
#include <hip/hip_runtime.h>
#include <cstdint>
#include <cstddef>

#define S_LEN  2048
#define D_MODEL 1024
#define D_FF   2048
#define NLAYER 4
// H=8, DK=128, WINDOW=64 (half=32)

typedef float  f32x4  __attribute__((ext_vector_type(4)));
typedef __bf16 bf16x8 __attribute__((ext_vector_type(8)));

#define ATT_SCALE 0.08838834764831845f   // 1/sqrt(128)

__device__ __forceinline__ void async_copy16(const void* g, void* s) {
    __builtin_amdgcn_global_load_lds((const __attribute__((address_space(1))) void*)g,
                                     (__attribute__((address_space(3))) void*)s, 16, 0, 0);
}

template<int NW>
__device__ __forceinline__ float blockRedSum(float v, float* red) {
    #pragma unroll
    for (int off = 32; off > 0; off >>= 1) v += __shfl_down(v, off);
    const int t = threadIdx.x;
    if ((t & 63) == 0) red[t >> 6] = v;
    __syncthreads();
    float r = red[0];
    #pragma unroll
    for (int i = 1; i < NW; i++) r += red[i];
    __syncthreads();
    return r;
}

// blocks 0..2047: x = 2*enc + pe (fp32 + bf16). block 2048: mask setup.
__global__ __launch_bounds__(256)
void init_mask_kernel(const float* __restrict__ enc, float* __restrict__ x,
                      __bf16* __restrict__ xb, const int* __restrict__ gidx,
                      int* __restrict__ isg, int* __restrict__ gcols, int* __restrict__ ngc) {
    const int t = threadIdx.x;
    if (blockIdx.x < S_LEN) {
        const int s = blockIdx.x;
        #pragma unroll
        for (int i = 0; i < 4; i++) {
            const int d = t + i * 256;
            const float freq = expf(-(float)(d & ~1) * (9.210340371976184f / 1024.0f));
            const float ang = (float)s * freq;
            const float pe = (d & 1) ? cosf(ang) : sinf(ang);
            const float v = 2.0f * enc[(size_t)s * D_MODEL + d] + pe;
            x[(size_t)s * D_MODEL + d] = v;
            xb[(size_t)s * D_MODEL + d] = (__bf16)v;
        }
    } else {
        __shared__ int gsh[32];
        __shared__ int cnt;
        if (t < 32) {
            const int g = gidx[t] / 15;      // gidx >= 0
            gsh[t] = (g >= 0 && g < S_LEN) ? g : -1;
        }
        if (t == 0) cnt = 0;
        __syncthreads();
        #pragma unroll
        for (int i = 0; i < 8; i++) {
            const int s = t + i * 256;
            int f = 0;
            #pragma unroll
            for (int j = 0; j < 32; j++) f |= (gsh[j] == s) ? 1 : 0;
            isg[s] = f;
            if (f) { const int p = atomicAdd(&cnt, 1); gcols[p] = s; }
        }
        __syncthreads();
        if (t == 0) *ngc = cnt;
    }
}

// All 6 weight transposes of one layer in a single dispatch; also zeroes vmean.
// fp32 [K][N] -> bf16 [N][K]. Arena (elements):
//   WqT 0..1M, WkT 1M..2M, WvT 2M..3M, WoT 3M..4M, W1T 4M..6M, W2T 6M..8M
__global__ __launch_bounds__(256)
void transpose_all_kernel(const float* __restrict__ Wq, const float* __restrict__ Wk,
                          const float* __restrict__ Wv, const float* __restrict__ Wo,
                          const float* __restrict__ W1, const float* __restrict__ W2,
                          __bf16* __restrict__ out, float* __restrict__ vmean) {
    int bid = blockIdx.x;
    if (bid < 4) vmean[bid * 256 + threadIdx.x] = 0.0f;   // consumed by NEXT dispatch
    const float* in; __bf16* o; int K, N, r;
    if (bid < 4096) {
        const int m = bid >> 10; r = bid & 1023; K = 1024; N = 1024;
        in = (m == 0) ? Wq : (m == 1) ? Wk : (m == 2) ? Wv : Wo;
        o  = out + (size_t)m * 1024 * 1024;
    } else {
        bid -= 4096;
        const int m = bid >> 11; r = bid & 2047;
        if (m == 0) { in = W1; K = 1024; N = 2048; o = out + (size_t)4 * 1024 * 1024; }
        else        { in = W2; K = 2048; N = 1024; o = out + (size_t)6 * 1024 * 1024; }
    }
    const int ntx = N >> 5;
    const int n0 = (r % ntx) * 32, k0 = (r / ntx) * 32;
    __shared__ float tile[32][33];
    const int tx = threadIdx.x & 31, ty = threadIdx.x >> 5;
    #pragma unroll
    for (int i = ty; i < 32; i += 8)
        tile[i][tx] = in[(size_t)(k0 + i) * N + n0 + tx];
    __syncthreads();
    #pragma unroll
    for (int i = ty; i < 32; i += 8)
        o[(size_t)(n0 + i) * K + k0 + tx] = (__bf16)tile[tx][i];
}

// C[M][N] = A[M][K] * Bt[N][K]^T. BK=64 (half the barrier drains of BK=32).
// EPI 0: fp32 out, 1: relu->bf16, 2: bf16.
// VACC: for cols >= 2048 (the V block of fused QKV), atomicAdd fp32 column sums
// into vmean (used by pad-row attention). vmean zeroed by the prior dispatch.
template<int BM, int BN, int EPI, bool VACC>
__global__ __launch_bounds__(256)
void gemm_bt(const __bf16* __restrict__ A, const __bf16* __restrict__ Bt,
             void* __restrict__ Cv, float* __restrict__ vmean, int M, int N, int K) {
    constexpr int WM = BM / 2, WN = BN / 2;
    constexpr int MI = WM / 16, NI = WN / 16;
    __shared__ __bf16 As[BM * 64];
    __shared__ __bf16 Bs[BN * 64];
    const int t = threadIdx.x;
    const int w = t >> 6, l = t & 63;
    const int l15 = l & 15, q4 = l >> 4;
    const int wr = w >> 1, wc = w & 1;
    const int m0 = blockIdx.y * BM, n0 = blockIdx.x * BN;

    const int srow = t >> 3;         // 0..31
    const int kc8  = (t & 7) * 8;    // element offset in 64-wide K-tile
    const __bf16* ag = A  + (size_t)(m0 + srow) * K + kc8;
    const __bf16* bg = Bt + (size_t)(n0 + srow) * K + kc8;
    __bf16* asw = As + w * 512;      // wave-uniform LDS base (w*1024 bytes)
    __bf16* bsw = Bs + w * 512;

    const int aoff = (wr * WM + l15) * 64 + q4 * 8;
    const int boff = (wc * WN + l15) * 64 + q4 * 8;

    f32x4 acc[MI][NI];
    #pragma unroll
    for (int i = 0; i < MI; i++)
        #pragma unroll
        for (int j = 0; j < NI; j++) acc[i][j] = (f32x4){0.f, 0.f, 0.f, 0.f};

    for (int k0 = 0; k0 < K; k0 += 64) {
        // stage A (BM x 64) and B (BN x 64), 32 rows per copy round
        async_copy16(ag + k0, asw);
        async_copy16(ag + (size_t)32 * K + k0, asw + 2048);
        if constexpr (BM == 128) {
            async_copy16(ag + (size_t)64 * K + k0, asw + 4096);
            async_copy16(ag + (size_t)96 * K + k0, asw + 6144);
        }
        async_copy16(bg + k0, bsw);
        async_copy16(bg + (size_t)32 * K + k0, bsw + 2048);
        if constexpr (BN == 128) {
            async_copy16(bg + (size_t)64 * K + k0, bsw + 4096);
            async_copy16(bg + (size_t)96 * K + k0, bsw + 6144);
        }
        __syncthreads();
        #pragma unroll
        for (int s = 0; s < 64; s += 32) {
            bf16x8 af[MI], bfr[NI];
            #pragma unroll
            for (int i = 0; i < MI; i++) af[i]  = *(const bf16x8*)(As + aoff + i * 1024 + s);
            #pragma unroll
            for (int j = 0; j < NI; j++) bfr[j] = *(const bf16x8*)(Bs + boff + j * 1024 + s);
            #pragma unroll
            for (int i = 0; i < MI; i++)
                #pragma unroll
                for (int j = 0; j < NI; j++)
                    acc[i][j] = __builtin_amdgcn_mfma_f32_16x16x32_bf16(af[i], bfr[j], acc[i][j], 0, 0, 0);
        }
        __syncthreads();
    }

    const int r0 = m0 + wr * WM + q4 * 4;
    const int c0 = n0 + wc * WN + l15;
    if constexpr (EPI == 0) {
        float* C = (float*)Cv;
        #pragma unroll
        for (int i = 0; i < MI; i++)
            #pragma unroll
            for (int j = 0; j < NI; j++)
                #pragma unroll
                for (int r = 0; r < 4; r++)
                    C[(size_t)(r0 + i * 16 + r) * N + c0 + j * 16] = acc[i][j][r];
    } else if constexpr (EPI == 1) {
        __bf16* C = (__bf16*)Cv;
        #pragma unroll
        for (int i = 0; i < MI; i++)
            #pragma unroll
            for (int j = 0; j < NI; j++)
                #pragma unroll
                for (int r = 0; r < 4; r++)
                    C[(size_t)(r0 + i * 16 + r) * N + c0 + j * 16] = (__bf16)fmaxf(acc[i][j][r], 0.0f);
    } else {
        __bf16* C = (__bf16*)Cv;
        #pragma unroll
        for (int i = 0; i < MI; i++)
            #pragma unroll
            for (int j = 0; j < NI; j++)
                #pragma unroll
                for (int r = 0; r < 4; r++)
                    C[(size_t)(r0 + i * 16 + r) * N + c0 + j * 16] = (__bf16)acc[i][j][r];
    }
    if constexpr (VACC) {
        #pragma unroll
        for (int j = 0; j < NI; j++) {
            const int col = c0 + j * 16;
            if (col >= 2048) {                       // V block; uniform per wave+j
                float s = 0.f;
                #pragma unroll
                for (int i = 0; i < MI; i++)
                    #pragma unroll
                    for (int r = 0; r < 4; r++) s += acc[i][j][r];
                s += __shfl_xor(s, 16);
                s += __shfl_xor(s, 32);
                if (q4 == 0) atomicAdd(&vmean[col - 2048], s);
            }
        }
    }
}

// ---------------- MFMA attention (bf16 qkv input) ----------------
__global__ __launch_bounds__(256)
void attn_local(const __bf16* __restrict__ qkvb, const int* __restrict__ Tp,
                const int* __restrict__ isg, const int* __restrict__ gcols,
                const int* __restrict__ ngcp, const float* __restrict__ vmean,
                __bf16* __restrict__ ctx) {
    const int qt0 = blockIdx.x * 32, h = blockIdx.y, hd = h * 128;
    const int t = threadIdx.x;
    __shared__ __bf16 Qs[32 * 136];
    __shared__ __bf16 Ks[128 * 136];
    __shared__ __bf16 Vs[128 * 136];
    __shared__ __bf16 Ps[32 * 136];
    __shared__ float  Ss[32 * 129];
    __shared__ int cix[128], cgf[128], rtype[32];
    __shared__ int ncs;
    const int T = *Tp, ng = *ngcp;
    const int wl = max(qt0 - 32, 0), wh = min(qt0 + 63, S_LEN - 1);
    if (t == 0) ncs = 0;
    if (t < 32) { const int qr = qt0 + t; rtype[t] = isg[qr] ? 1 : (qr < T ? 0 : 2); }
    __syncthreads();
    if (t <= wh - wl) {
        const int c = wl + t, gf = isg[c];
        if (c < T || gf) { const int p = atomicAdd(&ncs, 1); cix[p] = c; cgf[p] = gf; }
    }
    if (t < ng) {
        const int c = gcols[t];
        if (c < wl || c > wh) { const int p = atomicAdd(&ncs, 1); cix[p] = c; cgf[p] = 1; }
    }
    // stage Q
    {
        const int r = t >> 3, d0 = (t & 7) * 16;
        const bf16x8* src = (const bf16x8*)(qkvb + (size_t)(qt0 + r) * 3072 + hd + d0);
        *(bf16x8*)&Qs[r * 136 + d0]     = src[0];
        *(bf16x8*)&Qs[r * 136 + d0 + 8] = src[1];
    }
    __syncthreads();
    const int nc = ncs;
    if (nc + t < 128) { cix[nc + t] = -1; cgf[nc + t] = 0; }   // sentinels
    // stage K/V
    {
        const int j = t >> 1, d0 = (t & 1) * 64;
        const int ci = (j < nc) ? cix[j] : -1;
        if (ci >= 0) {
            const bf16x8* kp = (const bf16x8*)(qkvb + (size_t)ci * 3072 + 1024 + hd + d0);
            const bf16x8* vp = (const bf16x8*)(qkvb + (size_t)ci * 3072 + 2048 + hd + d0);
            #pragma unroll
            for (int i = 0; i < 8; i++) {
                *(bf16x8*)&Ks[j * 136 + d0 + i * 8] = kp[i];
                *(bf16x8*)&Vs[j * 136 + d0 + i * 8] = vp[i];
            }
        } else {
            #pragma unroll
            for (int i = 0; i < 8; i++) {
                *(bf16x8*)&Ks[j * 136 + d0 + i * 8] = (bf16x8)(__bf16)0.f;
                *(bf16x8*)&Vs[j * 136 + d0 + i * 8] = (bf16x8)(__bf16)0.f;
            }
        }
    }
    __syncthreads();

    const int l = t & 63, w = t >> 6;
    const int l15 = l & 15, q4 = l >> 4;
    const int nb = w * 32;
    // S = Q K^T
    {
        f32x4 sacc[2][2];
        #pragma unroll
        for (int i = 0; i < 2; i++)
            #pragma unroll
            for (int j = 0; j < 2; j++) sacc[i][j] = (f32x4){0.f, 0.f, 0.f, 0.f};
        #pragma unroll
        for (int kk = 0; kk < 4; kk++) {
            const int k0 = kk * 32;
            bf16x8 af[2], bk[2];
            af[0] = *(const bf16x8*)&Qs[l15 * 136 + k0 + q4 * 8];
            af[1] = *(const bf16x8*)&Qs[(16 + l15) * 136 + k0 + q4 * 8];
            bk[0] = *(const bf16x8*)&Ks[(nb + l15) * 136 + k0 + q4 * 8];
            bk[1] = *(const bf16x8*)&Ks[(nb + 16 + l15) * 136 + k0 + q4 * 8];
            #pragma unroll
            for (int m2 = 0; m2 < 2; m2++)
                #pragma unroll
                for (int n2 = 0; n2 < 2; n2++)
                    sacc[m2][n2] = __builtin_amdgcn_mfma_f32_16x16x32_bf16(af[m2], bk[n2], sacc[m2][n2], 0, 0, 0);
        }
        #pragma unroll
        for (int m2 = 0; m2 < 2; m2++)
            #pragma unroll
            for (int n2 = 0; n2 < 2; n2++)
                #pragma unroll
                for (int r = 0; r < 4; r++) {
                    const int row = m2 * 16 + q4 * 4 + r;
                    const int col = nb + n2 * 16 + l15;
                    const int c = cix[col];
                    const int dd = qt0 + row - c;
                    const bool ok = (c >= 0) && (((unsigned)(dd + 32) <= 64u) || cgf[col]);
                    Ss[row * 129 + col] = ok ? sacc[m2][n2][r] * ATT_SCALE : -1e30f;
                }
    }
    __syncthreads();
    // softmax (normalized) -> Ps bf16
    {
        const int r = t >> 3, i = t & 7;
        float mx = -1e30f;
        for (int c = i; c < 128; c += 8) mx = fmaxf(mx, Ss[r * 129 + c]);
        #pragma unroll
        for (int off = 4; off > 0; off >>= 1) mx = fmaxf(mx, __shfl_down(mx, off, 8));
        mx = __shfl(mx, 0, 8);
        float sm = 0.f;
        for (int c = i; c < 128; c += 8) {
            const float s = Ss[r * 129 + c];
            const float p = (s > -1e29f) ? __expf(s - mx) : 0.f;
            Ss[r * 129 + c] = p;
            sm += p;
        }
        #pragma unroll
        for (int off = 4; off > 0; off >>= 1) sm += __shfl_down(sm, off, 8);
        sm = __shfl(sm, 0, 8);
        const float rl = 1.0f / fmaxf(sm, 1e-30f);
        for (int c = i; c < 128; c += 8) Ps[r * 136 + c] = (__bf16)(Ss[r * 129 + c] * rl);
    }
    __syncthreads();
    // O = P V
    {
        f32x4 oacc[2][2];
        #pragma unroll
        for (int i = 0; i < 2; i++)
            #pragma unroll
            for (int j = 0; j < 2; j++) oacc[i][j] = (f32x4){0.f, 0.f, 0.f, 0.f};
        #pragma unroll
        for (int kk = 0; kk < 4; kk++) {
            const int k0 = kk * 32;
            bf16x8 ap[2], bv[2];
            ap[0] = *(const bf16x8*)&Ps[l15 * 136 + k0 + q4 * 8];
            ap[1] = *(const bf16x8*)&Ps[(16 + l15) * 136 + k0 + q4 * 8];
            #pragma unroll
            for (int n2 = 0; n2 < 2; n2++) {
                const int dimn = nb + n2 * 16 + l15;
                #pragma unroll
                for (int jj = 0; jj < 8; jj++)
                    bv[n2][jj] = Vs[(k0 + q4 * 8 + jj) * 136 + dimn];
            }
            #pragma unroll
            for (int m2 = 0; m2 < 2; m2++)
                #pragma unroll
                for (int n2 = 0; n2 < 2; n2++)
                    oacc[m2][n2] = __builtin_amdgcn_mfma_f32_16x16x32_bf16(ap[m2], bv[n2], oacc[m2][n2], 0, 0, 0);
        }
        #pragma unroll
        for (int m2 = 0; m2 < 2; m2++)
            #pragma unroll
            for (int n2 = 0; n2 < 2; n2++)
                #pragma unroll
                for (int r = 0; r < 4; r++) {
                    const int row = m2 * 16 + q4 * 4 + r;
                    const int dim = nb + n2 * 16 + l15;
                    const int rt = rtype[row];
                    const size_t o = (size_t)(qt0 + row) * D_MODEL + hd + dim;
                    if (rt == 0)      ctx[o] = (__bf16)oacc[m2][n2][r];
                    else if (rt == 2) ctx[o] = (__bf16)(vmean[hd + dim] * (1.0f / 2048.0f));
                }
    }
}

// global rows, partial flash over one 128-col chunk. block = (chunk, head).
__global__ __launch_bounds__(256)
void attn_gpart(const __bf16* __restrict__ qkvb, const int* __restrict__ Tp,
                const int* __restrict__ isg, const int* __restrict__ gcols,
                const int* __restrict__ ngcp, float* __restrict__ Og,
                float* __restrict__ mg, float* __restrict__ lg) {
    const int cb = blockIdx.x, h = blockIdx.y, hd = h * 128, c0 = cb * 128;
    const int t = threadIdx.x;
    const int ng = *ngcp, T = *Tp;
    if (ng == 0) return;
    __shared__ __bf16 Qs[32 * 136];
    __shared__ __bf16 Ks[128 * 136];
    __shared__ __bf16 Vs[128 * 136];
    __shared__ __bf16 Ps[32 * 136];
    __shared__ float  Ss[32 * 129];
    __shared__ int vf[128];
    // stage Q (gathered global rows)
    {
        const int r = t >> 3, d0 = (t & 7) * 16;
        if (r < ng) {
            const bf16x8* src = (const bf16x8*)(qkvb + (size_t)gcols[r] * 3072 + hd + d0);
            *(bf16x8*)&Qs[r * 136 + d0]     = src[0];
            *(bf16x8*)&Qs[r * 136 + d0 + 8] = src[1];
        } else {
            *(bf16x8*)&Qs[r * 136 + d0]     = (bf16x8)(__bf16)0.f;
            *(bf16x8*)&Qs[r * 136 + d0 + 8] = (bf16x8)(__bf16)0.f;
        }
    }
    if (t < 128) { const int c = c0 + t; vf[t] = (c < T || isg[c]) ? 1 : 0; }
    // stage K/V chunk rows
    {
        const int j = t >> 1, d0 = (t & 1) * 64;
        const int ci = c0 + j;
        const bf16x8* kp = (const bf16x8*)(qkvb + (size_t)ci * 3072 + 1024 + hd + d0);
        const bf16x8* vp = (const bf16x8*)(qkvb + (size_t)ci * 3072 + 2048 + hd + d0);
        #pragma unroll
        for (int i = 0; i < 8; i++) {
            *(bf16x8*)&Ks[j * 136 + d0 + i * 8] = kp[i];
            *(bf16x8*)&Vs[j * 136 + d0 + i * 8] = vp[i];
        }
    }
    __syncthreads();

    const int l = t & 63, w = t >> 6;
    const int l15 = l & 15, q4 = l >> 4;
    const int nb = w * 32;
    {
        f32x4 sacc[2][2];
        #pragma unroll
        for (int i = 0; i < 2; i++)
            #pragma unroll
            for (int j = 0; j < 2; j++) sacc[i][j] = (f32x4){0.f, 0.f, 0.f, 0.f};
        #pragma unroll
        for (int kk = 0; kk < 4; kk++) {
            const int k0 = kk * 32;
            bf16x8 af[2], bk[2];
            af[0] = *(const bf16x8*)&Qs[l15 * 136 + k0 + q4 * 8];
            af[1] = *(const bf16x8*)&Qs[(16 + l15) * 136 + k0 + q4 * 8];
            bk[0] = *(const bf16x8*)&Ks[(nb + l15) * 136 + k0 + q4 * 8];
            bk[1] = *(const bf16x8*)&Ks[(nb + 16 + l15) * 136 + k0 + q4 * 8];
            #pragma unroll
            for (int m2 = 0; m2 < 2; m2++)
                #pragma unroll
                for (int n2 = 0; n2 < 2; n2++)
                    sacc[m2][n2] = __builtin_amdgcn_mfma_f32_16x16x32_bf16(af[m2], bk[n2], sacc[m2][n2], 0, 0, 0);
        }
        #pragma unroll
        for (int m2 = 0; m2 < 2; m2++)
            #pragma unroll
            for (int n2 = 0; n2 < 2; n2++)
                #pragma unroll
                for (int r = 0; r < 4; r++) {
                    const int row = m2 * 16 + q4 * 4 + r;
                    const int col = nb + n2 * 16 + l15;
                    Ss[row * 129 + col] = vf[col] ? sacc[m2][n2][r] * ATT_SCALE : -1e30f;
                }
    }
    __syncthreads();
    // partial softmax: p = exp(s - m_c) (UNnormalized); save m_c, l_c
    {
        const int r = t >> 3, i = t & 7;
        float mx = -1e30f;
        for (int c = i; c < 128; c += 8) mx = fmaxf(mx, Ss[r * 129 + c]);
        #pragma unroll
        for (int off = 4; off > 0; off >>= 1) mx = fmaxf(mx, __shfl_down(mx, off, 8));
        mx = __shfl(mx, 0, 8);
        float sm = 0.f;
        for (int c = i; c < 128; c += 8) {
            const float s = Ss[r * 129 + c];
            const float p = (s > -1e29f) ? __expf(s - mx) : 0.f;
            Ps[r * 136 + c] = (__bf16)p;
            sm += p;
        }
        #pragma unroll
        for (int off = 4; off > 0; off >>= 1) sm += __shfl_down(sm, off, 8);
        if (i == 0) { mg[(h * 16 + cb) * 32 + r] = mx; lg[(h * 16 + cb) * 32 + r] = sm; }
    }
    __syncthreads();
    // O_c = P V
    {
        f32x4 oacc[2][2];
        #pragma unroll
        for (int i = 0; i < 2; i++)
            #pragma unroll
            for (int j = 0; j < 2; j++) oacc[i][j] = (f32x4){0.f, 0.f, 0.f, 0.f};
        #pragma unroll
        for (int kk = 0; kk < 4; kk++) {
            const int k0 = kk * 32;
            bf16x8 ap[2], bv[2];
            ap[0] = *(const bf16x8*)&Ps[l15 * 136 + k0 + q4 * 8];
            ap[1] = *(const bf16x8*)&Ps[(16 + l15) * 136 + k0 + q4 * 8];
            #pragma unroll
            for (int n2 = 0; n2 < 2; n2++) {
                const int dimn = nb + n2 * 16 + l15;
                #pragma unroll
                for (int jj = 0; jj < 8; jj++)
                    bv[n2][jj] = Vs[(k0 + q4 * 8 + jj) * 136 + dimn];
            }
            #pragma unroll
            for (int m2 = 0; m2 < 2; m2++)
                #pragma unroll
                for (int n2 = 0; n2 < 2; n2++)
                    oacc[m2][n2] = __builtin_amdgcn_mfma_f32_16x16x32_bf16(ap[m2], bv[n2], oacc[m2][n2], 0, 0, 0);
        }
        #pragma unroll
        for (int m2 = 0; m2 < 2; m2++)
            #pragma unroll
            for (int n2 = 0; n2 < 2; n2++)
                #pragma unroll
                for (int r = 0; r < 4; r++) {
                    const int row = m2 * 16 + q4 * 4 + r;
                    const int dim = nb + n2 * 16 + l15;
                    Og[((size_t)(h * 16 + cb) * 32 + row) * 128 + dim] = oacc[m2][n2][r];
                }
    }
}

// combine the 16 chunks for global rows
__global__ __launch_bounds__(256)
void attn_gcomb(const int* __restrict__ gcols, const int* __restrict__ ngcp,
                const float* __restrict__ Og, const float* __restrict__ mg,
                const float* __restrict__ lg, __bf16* __restrict__ ctx) {
    const int h = blockIdx.x, hd = h * 128, t = threadIdx.x;
    const int ng = *ngcp;
    const int r = t >> 3, i = t & 7;
    if (r >= ng) return;
    float M = -1e30f;
    #pragma unroll
    for (int cb = 0; cb < 16; cb++) M = fmaxf(M, mg[(h * 16 + cb) * 32 + r]);
    float e[16], L = 0.f;
    #pragma unroll
    for (int cb = 0; cb < 16; cb++) {
        e[cb] = __expf(mg[(h * 16 + cb) * 32 + r] - M);
        L += e[cb] * lg[(h * 16 + cb) * 32 + r];
    }
    const float rL = 1.0f / fmaxf(L, 1e-30f);
    const int grow = gcols[r];
    for (int d = i; d < 128; d += 8) {
        float o = 0.f;
        #pragma unroll
        for (int cb = 0; cb < 16; cb++)
            o += e[cb] * Og[((size_t)(h * 16 + cb) * 32 + r) * 128 + d];
        ctx[(size_t)grow * D_MODEL + hd + d] = (__bf16)(o * rL);
    }
}

// x = LN(y + r); writes fp32 (xo) + bf16 (xb)
__global__ __launch_bounds__(256)
void ln_kernel(const float* __restrict__ y, const float* __restrict__ r,
               const float* __restrict__ g, const float* __restrict__ b,
               float* __restrict__ xo, __bf16* __restrict__ xb) {
    const int row = blockIdx.x, t = threadIdx.x;
    const float* yr = y + (size_t)row * D_MODEL;
    const float* rr = r + (size_t)row * D_MODEL;
    __shared__ float red[4];
    float v[4]; float s = 0.f;
    #pragma unroll
    for (int i = 0; i < 4; i++) { const int d = t + i * 256; v[i] = yr[d] + rr[d]; s += v[i]; }
    s = blockRedSum<4>(s, red);
    const float mu = s * (1.0f / 1024.0f);
    float vs = 0.f;
    #pragma unroll
    for (int i = 0; i < 4; i++) { const float dd = v[i] - mu; vs += dd * dd; }
    vs = blockRedSum<4>(vs, red);
    const float rstd = rsqrtf(vs * (1.0f / 1024.0f) + 1e-5f);
    #pragma unroll
    for (int i = 0; i < 4; i++) {
        const int d = t + i * 256;
        const float o = g[d] * (v[i] - mu) * rstd + b[d];
        xo[(size_t)row * D_MODEL + d] = o;
        xb[(size_t)row * D_MODEL + d] = (__bf16)o;
    }
}

extern "C" void kernel_launch(void* const* d_in, const int* in_sizes, int n_in,
                              void* d_out, int out_size, void* d_ws, size_t ws_size,
                              hipStream_t stream) {
    const int*   Tp   = (const int*)  d_in[0];
    const float* enc  = (const float*)d_in[1];
    const int*   gidx = (const int*)  d_in[2];
    const float* Wq   = (const float*)d_in[3];
    const float* Wk   = (const float*)d_in[4];
    const float* Wv   = (const float*)d_in[5];
    const float* Wo   = (const float*)d_in[6];
    const float* ln1g = (const float*)d_in[7];
    const float* ln1b = (const float*)d_in[8];
    const float* W1   = (const float*)d_in[9];
    const float* W2   = (const float*)d_in[10];
    const float* ln2g = (const float*)d_in[11];
    const float* ln2b = (const float*)d_in[12];

    char* p = (char*)d_ws;
    size_t off = 0;
    auto alloc = [&](size_t bytes) -> void* {
        void* q = p + off;
        off += (bytes + 255) & ~(size_t)255;
        return q;
    };
    float*  x     = (float*) alloc((size_t)S_LEN * D_MODEL * 4);
    __bf16* xb    = (__bf16*)alloc((size_t)S_LEN * D_MODEL * 2);
    __bf16* qkvb  = (__bf16*)alloc((size_t)S_LEN * 3072 * 2);
    __bf16* ctx   = (__bf16*)alloc((size_t)S_LEN * D_MODEL * 2);
    float*  g1    = (float*) alloc((size_t)S_LEN * D_MODEL * 4);
    __bf16* h1    = (__bf16*)alloc((size_t)S_LEN * D_FF * 2);
    __bf16* wT    = (__bf16*)alloc((size_t)8 * 1024 * 1024 * 2);   // 6-matrix arena
    float*  vmean = (float*) alloc(1024 * 4);
    int*    isg   = (int*)   alloc(S_LEN * 4);
    int*    gcols = (int*)   alloc(S_LEN * 4);
    int*    ngc   = (int*)   alloc(256);
    float*  Og    = (float*) alloc((size_t)8 * 16 * 32 * 128 * 4);
    float*  mgb   = (float*) alloc(8 * 16 * 32 * 4);
    float*  lgb   = (float*) alloc(8 * 16 * 32 * 4);

    init_mask_kernel<<<S_LEN + 1, 256, 0, stream>>>(enc, x, xb, gidx, isg, gcols, ngc);

    for (int l = 0; l < NLAYER; l++) {
        const size_t lw = (size_t)l * 1024 * 1024;
        const size_t lf = (size_t)l * 1024 * 2048;
        transpose_all_kernel<<<8192, 256, 0, stream>>>(Wq + lw, Wk + lw, Wv + lw, Wo + lw,
                                                       W1 + lf, W2 + lf, wT, vmean);
        // --- QKV projection (fused N=3072, bf16 out + fused vmean), 64x128 tiles ---
        gemm_bt<64, 128, 2, true><<<dim3(24, 32), 256, 0, stream>>>(xb, wT, (void*)qkvb, vmean, S_LEN, 3072, 1024);

        // --- attention (MFMA, local/global/pad split) ---
        attn_local<<<dim3(64, 8), 256, 0, stream>>>(qkvb, Tp, isg, gcols, ngc, vmean, ctx);
        attn_gpart<<<dim3(16, 8), 256, 0, stream>>>(qkvb, Tp, isg, gcols, ngc, Og, mgb, lgb);
        attn_gcomb<<<8, 256, 0, stream>>>(gcols, ngc, Og, mgb, lgb, ctx);

        // --- output projection + LN1 ---
        gemm_bt<64, 64, 0, false><<<dim3(16, 32), 256, 0, stream>>>(ctx, wT + (size_t)3 * 1024 * 1024, (void*)g1, nullptr, S_LEN, 1024, 1024);
        ln_kernel<<<S_LEN, 256, 0, stream>>>(g1, x, ln1g + l * 1024, ln1b + l * 1024, x, xb);

        // --- FFN ---
        gemm_bt<64, 64, 1, false><<<dim3(32, 32), 256, 0, stream>>>(xb, wT + (size_t)4 * 1024 * 1024, (void*)h1, nullptr, S_LEN, 2048, 1024);
        gemm_bt<64, 64, 0, false><<<dim3(16, 32), 256, 0, stream>>>(h1, wT + (size_t)6 * 1024 * 1024, (void*)g1, nullptr, S_LEN, 1024, 2048);
        float* xout = (l == NLAYER - 1) ? (float*)d_out : x;
        ln_kernel<<<S_LEN, 256, 0, stream>>>(g1, x, ln2g + l * 1024, ln2b + l * 1024, xout, xb);
    }
}